// Round 1
// baseline (427.966 us; speedup 1.0000x reference)
//
#include <hip/hip_runtime.h>
#include <hip/hip_bf16.h>
#include <cmath>

// ---------------------------------------------------------------------------
// Problem: MultiSynonymsAttention
//   c=50 s=4 d=768 b=4 t=1024 z=12 h=64
// Decomposition:
//   KS  = tanh(H @ WK_w + WK_b)            [4096][768]   (row = b*1024+t, col = z*64+h)
//   QS  = Q @ WQ_w + WQ_b                  [200][768]    (row = c*4+s)
//   WQL = ql @ WV_w + WV_b                 [50][768]
//   KW[b,c,z,t] = sum_h tanh(H[b,t,zh]) * WQL[c,zh]      [b][c][z][t]
//   out[b,c] = 0.25 * sum_{z,s} (sum_t e^{sc-m} KW) / (sum_t e^{sc-m})
//     where sc[t] = sum_h KS[b,t,zh]*QS[cs,zh]
// ---------------------------------------------------------------------------

template<bool TANH>
__global__ __launch_bounds__(256) void gemm_bias(
    const float* __restrict__ A, const float* __restrict__ B,
    const float* __restrict__ bias, float* __restrict__ C,
    int M, int N, int K)
{
    __shared__ float As[16][68];   // [k][m], padded
    __shared__ float Bs[16][68];   // [k][n], padded
    const int bm = blockIdx.y * 64, bn = blockIdx.x * 64;
    const int tid = threadIdx.x;
    const int tr = (tid >> 4) << 2;   // 0..60 (row offset in tile)
    const int tc = (tid & 15) << 2;   // 0..60 (col offset in tile)
    const int ar = tid >> 2, ak = (tid & 3) << 2;   // A-load: 64 rows x 16 k
    const int br = tid >> 4, bc = (tid & 15) << 2;  // B-load: 16 k x 64 cols
    float acc[4][4] = {};

    for (int k0 = 0; k0 < K; k0 += 16) {
        float4 av = make_float4(0.f, 0.f, 0.f, 0.f);
        if (bm + ar < M)
            av = *(const float4*)&A[(size_t)(bm + ar) * K + k0 + ak];
        As[ak + 0][ar] = av.x; As[ak + 1][ar] = av.y;
        As[ak + 2][ar] = av.z; As[ak + 3][ar] = av.w;
        float4 bv = *(const float4*)&B[(size_t)(k0 + br) * N + bn + bc];
        Bs[br][bc + 0] = bv.x; Bs[br][bc + 1] = bv.y;
        Bs[br][bc + 2] = bv.z; Bs[br][bc + 3] = bv.w;
        __syncthreads();
#pragma unroll
        for (int kk = 0; kk < 16; kk++) {
            float a0 = As[kk][tr + 0], a1 = As[kk][tr + 1];
            float a2 = As[kk][tr + 2], a3 = As[kk][tr + 3];
            float b0 = Bs[kk][tc + 0], b1 = Bs[kk][tc + 1];
            float b2 = Bs[kk][tc + 2], b3 = Bs[kk][tc + 3];
            acc[0][0] += a0 * b0; acc[0][1] += a0 * b1; acc[0][2] += a0 * b2; acc[0][3] += a0 * b3;
            acc[1][0] += a1 * b0; acc[1][1] += a1 * b1; acc[1][2] += a1 * b2; acc[1][3] += a1 * b3;
            acc[2][0] += a2 * b0; acc[2][1] += a2 * b1; acc[2][2] += a2 * b2; acc[2][3] += a2 * b3;
            acc[3][0] += a3 * b0; acc[3][1] += a3 * b1; acc[3][2] += a3 * b2; acc[3][3] += a3 * b3;
        }
        __syncthreads();
    }
#pragma unroll
    for (int i = 0; i < 4; i++) {
        int row = bm + tr + i;
        if (row < M) {
#pragma unroll
            for (int j = 0; j < 4; j++) {
                float v = acc[i][j] + bias[bn + tc + j];
                if (TANH) v = tanhf(v);
                C[(size_t)row * N + bn + tc + j] = v;
            }
        }
    }
}

// KW[b,c,z,t] = sum_h tanh(H[b,t,z*64+h]) * WQL[c*768 + z*64+h]
// block = (b, z, t-chunk of 64), 256 threads
__global__ __launch_bounds__(256) void kw_kernel(
    const float* __restrict__ H, const float* __restrict__ WQL,
    float* __restrict__ KW)
{
    const int blk = blockIdx.x;
    const int tchunk = blk & 15;
    const int z = (blk >> 4) % 12;
    const int b = blk / 192;
    const int t0 = tchunk * 64;
    const int tid = threadIdx.x;

    __shared__ float KHs[64][65];   // [t][h]
    __shared__ float WQs[50][65];   // [c][h]

#pragma unroll
    for (int i = 0; i < 4; i++) {
        int f = tid + i * 256;              // 0..1023
        int tt = f >> 4;
        int h4 = (f & 15) << 2;
        float4 v = *(const float4*)&H[((size_t)(b * 1024 + t0 + tt)) * 768 + z * 64 + h4];
        KHs[tt][h4 + 0] = tanhf(v.x);
        KHs[tt][h4 + 1] = tanhf(v.y);
        KHs[tt][h4 + 2] = tanhf(v.z);
        KHs[tt][h4 + 3] = tanhf(v.w);
    }
#pragma unroll
    for (int i = 0; i < 4; i++) {
        int g = tid + i * 256;              // 0..799 used
        if (g < 800) {
            int cc = g >> 4;
            int h4 = (g & 15) << 2;
            float4 v = *(const float4*)&WQL[(size_t)cc * 768 + z * 64 + h4];
            WQs[cc][h4 + 0] = v.x; WQs[cc][h4 + 1] = v.y;
            WQs[cc][h4 + 2] = v.z; WQs[cc][h4 + 3] = v.w;
        }
    }
    __syncthreads();

    const int t = tid & 63;
    const int cg = tid >> 6;
    for (int c = cg; c < 50; c += 4) {
        float acc = 0.f;
#pragma unroll 16
        for (int h = 0; h < 64; h++)
            acc += KHs[t][h] * WQs[c][h];
        KW[(((size_t)b * 50 + c) * 12 + z) * 1024 + t0 + t] = acc;
    }
}

// block = (b,c,z), 256 threads. Computes scores for 4 s-rows over t=1024,
// softmax, dots with KW, atomically accumulates into out[b,c].
__global__ __launch_bounds__(256) void attn_kernel(
    const float* __restrict__ KS, const float* __restrict__ QS,
    const float* __restrict__ KW, float* __restrict__ out)
{
    const int blk = blockIdx.x;
    const int z = blk % 12;
    const int c = (blk / 12) % 50;
    const int b = blk / 600;
    const int tid = threadIdx.x;

    __shared__ float qs[4][64];
    __shared__ float sc[4][1024];   // 16 KB

    // load q rows (c*4+s), cols z*64..+64 : 256 floats
    qs[tid >> 6][tid & 63] = QS[(size_t)(c * 4 + (tid >> 6)) * 768 + z * 64 + (tid & 63)];
    __syncthreads();

    // phase 1: scores. thread handles t = tid + k*256
#pragma unroll
    for (int k = 0; k < 4; k++) {
        const int t = tid + k * 256;
        const float* kr = &KS[(size_t)(b * 1024 + t) * 768 + z * 64];
        float a0 = 0.f, a1 = 0.f, a2 = 0.f, a3 = 0.f;
#pragma unroll
        for (int h4 = 0; h4 < 64; h4 += 4) {
            float4 kv = *(const float4*)&kr[h4];
            a0 += kv.x * qs[0][h4] + kv.y * qs[0][h4 + 1] + kv.z * qs[0][h4 + 2] + kv.w * qs[0][h4 + 3];
            a1 += kv.x * qs[1][h4] + kv.y * qs[1][h4 + 1] + kv.z * qs[1][h4 + 2] + kv.w * qs[1][h4 + 3];
            a2 += kv.x * qs[2][h4] + kv.y * qs[2][h4 + 1] + kv.z * qs[2][h4 + 2] + kv.w * qs[2][h4 + 3];
            a3 += kv.x * qs[3][h4] + kv.y * qs[3][h4 + 1] + kv.z * qs[3][h4 + 2] + kv.w * qs[3][h4 + 3];
        }
        sc[0][t] = a0; sc[1][t] = a1; sc[2][t] = a2; sc[3][t] = a3;
    }
    __syncthreads();

    // phase 2: per-wave softmax + KW dot. wave w handles s=w.
    const int s = tid >> 6;
    const int lane = tid & 63;
    const float* kwrow = &KW[(((size_t)b * 50 + c) * 12 + z) * 1024];

    float m = -INFINITY;
#pragma unroll
    for (int k = 0; k < 16; k++)
        m = fmaxf(m, sc[s][lane + k * 64]);
#pragma unroll
    for (int off = 32; off; off >>= 1)
        m = fmaxf(m, __shfl_xor(m, off));

    float den = 0.f, num = 0.f;
#pragma unroll
    for (int k = 0; k < 16; k++) {
        int t = lane + k * 64;
        float p = __expf(sc[s][t] - m);
        den += p;
        num += p * kwrow[t];
    }
#pragma unroll
    for (int off = 32; off; off >>= 1) {
        den += __shfl_xor(den, off);
        num += __shfl_xor(num, off);
    }
    if (lane == 0)
        atomicAdd(&out[b * 50 + c], 0.25f * num / den);
}

extern "C" void kernel_launch(void* const* d_in, const int* in_sizes, int n_in,
                              void* d_out, int out_size, void* d_ws, size_t ws_size,
                              hipStream_t stream) {
    const float* Q    = (const float*)d_in[0];
    const float* H    = (const float*)d_in[1];
    const float* ql   = (const float*)d_in[2];
    const float* WQ_w = (const float*)d_in[3];
    const float* WQ_b = (const float*)d_in[4];
    const float* WK_w = (const float*)d_in[5];
    const float* WK_b = (const float*)d_in[6];
    const float* WV_w = (const float*)d_in[7];
    const float* WV_b = (const float*)d_in[8];
    float* out = (float*)d_out;

    float* ws  = (float*)d_ws;
    float* KS  = ws;                 // 4096*768   = 3,145,728 f
    float* QS  = KS + 3145728;       // 200*768    =   153,600 f
    float* WQL = QS + 153600;        // 50*768     =    38,400 f
    float* KW  = WQL + 38400;        // 4*50*12*1024 = 2,457,600 f
    (void)in_sizes; (void)n_in; (void)out_size; (void)ws_size;

    hipMemsetAsync(d_out, 0, 200 * sizeof(float), stream);

    // KS = tanh(H @ WK_w + WK_b)   M=4096 N=768 K=768
    gemm_bias<true ><<<dim3(12, 64), 256, 0, stream>>>(H, WK_w, WK_b, KS, 4096, 768, 768);
    // QS = Q @ WQ_w + WQ_b         M=200
    gemm_bias<false><<<dim3(12, 4), 256, 0, stream>>>(Q, WQ_w, WQ_b, QS, 200, 768, 768);
    // WQL = ql @ WV_w + WV_b       M=50
    gemm_bias<false><<<dim3(12, 1), 256, 0, stream>>>(ql, WV_w, WV_b, WQL, 50, 768, 768);
    // KW[b,c,z,t]
    kw_kernel<<<768, 256, 0, stream>>>(H, WQL, KW);
    // attention + reduction
    attn_kernel<<<2400, 256, 0, stream>>>(KS, QS, KW, out);
}

// Round 3
// 423.494 us; speedup vs baseline: 1.0106x; 1.0106x over previous
//
#include <hip/hip_runtime.h>
#include <hip/hip_bf16.h>
#include <cmath>

// ---------------------------------------------------------------------------
// MultiSynonymsAttention: c=50 s=4 d=768 b=4 t=1024 z=12 h=64
//   KS  = tanh(H @ WK_w + WK_b)            [4096][768]
//   QS  = Q @ WQ_w + WQ_b                  [200][768]
//   WQL = ql @ WV_w + WV_b                 [50][768]
//   KW[b,c,z,t] = sum_h tanh(H[b,t,zh]) * WQL[c,zh]
//   out[b,c] = 0.25 * sum_{z,s} softmax_t(KS.QS) . KW
// ---------------------------------------------------------------------------

// fp32 GEMM, 64x64 tile, BK=16, 128 threads, 8x4 acc per thread.
template<bool TANH>
__global__ __launch_bounds__(128) void gemm_bias(
    const float* __restrict__ A, const float* __restrict__ B,
    const float* __restrict__ bias, float* __restrict__ C,
    int M, int N, int K)
{
    __shared__ float As[16][68];   // [k][m]
    __shared__ float Bs[16][68];   // [k][n]
    const int bm = blockIdx.y * 64, bn = blockIdx.x * 64;
    const int tid = threadIdx.x;
    const int row0 = (tid >> 4) << 3;   // 0..56
    const int col0 = (tid & 15) << 2;   // 0..60
    float acc[8][4] = {};

    for (int k0 = 0; k0 < K; k0 += 16) {
        // A tile: 64 rows x 16 k = 256 float4, transposed into As[k][m]
#pragma unroll
        for (int i = 0; i < 2; i++) {
            int f = tid + i * 128;
            int ar = f >> 2, ak4 = (f & 3) << 2;
            float4 av = make_float4(0.f, 0.f, 0.f, 0.f);
            if (bm + ar < M)
                av = *(const float4*)&A[(size_t)(bm + ar) * K + k0 + ak4];
            As[ak4 + 0][ar] = av.x; As[ak4 + 1][ar] = av.y;
            As[ak4 + 2][ar] = av.z; As[ak4 + 3][ar] = av.w;
        }
        // B tile: 16 k x 64 cols = 256 float4
#pragma unroll
        for (int i = 0; i < 2; i++) {
            int f = tid + i * 128;
            int bk = f >> 4, bc = (f & 15) << 2;
            float4 bv = *(const float4*)&B[(size_t)(k0 + bk) * N + bn + bc];
            *(float4*)&Bs[bk][bc] = bv;
        }
        __syncthreads();
#pragma unroll
        for (int kk = 0; kk < 16; kk++) {
            float4 b0 = *(const float4*)&Bs[kk][col0];
            float4 a0 = *(const float4*)&As[kk][row0];
            float4 a1 = *(const float4*)&As[kk][row0 + 4];
            float ar8[8] = {a0.x, a0.y, a0.z, a0.w, a1.x, a1.y, a1.z, a1.w};
#pragma unroll
            for (int i = 0; i < 8; i++) {
                acc[i][0] += ar8[i] * b0.x;
                acc[i][1] += ar8[i] * b0.y;
                acc[i][2] += ar8[i] * b0.z;
                acc[i][3] += ar8[i] * b0.w;
            }
        }
        __syncthreads();
    }
    float4 bv = *(const float4*)&bias[bn + col0];
#pragma unroll
    for (int i = 0; i < 8; i++) {
        int row = bm + row0 + i;
        if (row < M) {
            float4 v;
            v.x = acc[i][0] + bv.x; v.y = acc[i][1] + bv.y;
            v.z = acc[i][2] + bv.z; v.w = acc[i][3] + bv.w;
            if (TANH) {
                v.x = tanhf(v.x); v.y = tanhf(v.y);
                v.z = tanhf(v.z); v.w = tanhf(v.w);
            }
            *(float4*)&C[(size_t)row * N + bn + col0] = v;
        }
    }
}

// KW[b,c,z,t] = sum_h tanh(H[b,t,z*64+h]) * WQL[c*768 + z*64+h]
__global__ __launch_bounds__(256) void kw_kernel(
    const float* __restrict__ H, const float* __restrict__ WQL,
    float* __restrict__ KW)
{
    const int blk = blockIdx.x;
    const int tchunk = blk & 15;
    const int z = (blk >> 4) % 12;
    const int b = blk / 192;
    const int t0 = tchunk * 64;
    const int tid = threadIdx.x;

    __shared__ float KHs[64][65];
    __shared__ float WQs[50][65];

#pragma unroll
    for (int i = 0; i < 4; i++) {
        int f = tid + i * 256;
        int tt = f >> 4;
        int h4 = (f & 15) << 2;
        float4 v = *(const float4*)&H[((size_t)(b * 1024 + t0 + tt)) * 768 + z * 64 + h4];
        KHs[tt][h4 + 0] = tanhf(v.x);
        KHs[tt][h4 + 1] = tanhf(v.y);
        KHs[tt][h4 + 2] = tanhf(v.z);
        KHs[tt][h4 + 3] = tanhf(v.w);
    }
#pragma unroll
    for (int i = 0; i < 4; i++) {
        int g = tid + i * 256;
        if (g < 800) {
            int cc = g >> 4;
            int h4 = (g & 15) << 2;
            float4 v = *(const float4*)&WQL[(size_t)cc * 768 + z * 64 + h4];
            WQs[cc][h4 + 0] = v.x; WQs[cc][h4 + 1] = v.y;
            WQs[cc][h4 + 2] = v.z; WQs[cc][h4 + 3] = v.w;
        }
    }
    __syncthreads();

    const int t = tid & 63;
    const int cg = tid >> 6;
    for (int c = cg; c < 50; c += 4) {
        float acc = 0.f;
#pragma unroll 16
        for (int h = 0; h < 64; h++)
            acc += KHs[t][h] * WQs[c][h];
        KW[(((size_t)b * 50 + c) * 12 + z) * 1024 + t0 + t] = acc;
    }
}

// Flash-style attention + reduction.
// block = (b, z, c-group of 5); 256 threads = 4 waves; wave handles 5 rows
// (row r = 5w+j -> class c0 + (r>>2), synonym r&3, QS row c0*4+r).
// Online softmax with scalar num/den accumulators; atomicAdd into out[b,c].
__global__ __launch_bounds__(256) void attn2_kernel(
    const float* __restrict__ KS, const float* __restrict__ QS,
    const float* __restrict__ KW, float* __restrict__ out)
{
    const int blk = blockIdx.x;
    const int cg = blk % 10;
    const int z  = (blk / 10) % 12;
    const int b  = blk / 120;
    const int c0 = cg * 5;
    const int tid = threadIdx.x;
    const int lane = tid & 63;
    const int w = tid >> 6;

    __shared__ float KSs[128][68];   // 34.8 KB, pad-68: even bank spread
    __shared__ float qs[20][68];     // 5.4 KB

    for (int f = tid; f < 320; f += 256) {
        int r = f >> 4, slot = f & 15;
        float4 v = *(const float4*)&QS[(size_t)(c0 * 4 + r) * 768 + z * 64 + slot * 4];
        *(float4*)&qs[r][slot << 2] = v;
    }

    float m[5], den[5], num[5];
#pragma unroll
    for (int j = 0; j < 5; j++) { m[j] = -INFINITY; den[j] = 0.f; num[j] = 0.f; }

    const float* kwbase = &KW[(((size_t)b * 50 + c0) * 12 + z) * 1024];

    for (int t0 = 0; t0 < 1024; t0 += 128) {
        __syncthreads();
        // stage KS rows t0..t0+127 (64 cols) coalesced
#pragma unroll
        for (int i = 0; i < 8; i++) {
            int f = tid + i * 256;
            int row = f >> 4, slot = f & 15;
            float4 v = *(const float4*)&KS[(size_t)(b * 1024 + t0 + row) * 768 + z * 64 + slot * 4];
            *(float4*)&KSs[row][slot << 2] = v;
        }
        __syncthreads();

        float s0[5] = {0.f, 0.f, 0.f, 0.f, 0.f};
        float s1[5] = {0.f, 0.f, 0.f, 0.f, 0.f};
#pragma unroll
        for (int h4 = 0; h4 < 16; h4++) {
            float4 k0 = *(const float4*)&KSs[lane][h4 << 2];
            float4 k1 = *(const float4*)&KSs[lane + 64][h4 << 2];
#pragma unroll
            for (int j = 0; j < 5; j++) {
                float4 q = *(const float4*)&qs[5 * w + j][h4 << 2];
                s0[j] += k0.x * q.x + k0.y * q.y + k0.z * q.z + k0.w * q.w;
                s1[j] += k1.x * q.x + k1.y * q.y + k1.z * q.z + k1.w * q.w;
            }
        }
#pragma unroll
        for (int j = 0; j < 5; j++) {
            int r = 5 * w + j;
            float kw0 = kwbase[(size_t)(r >> 2) * 12288 + t0 + lane];
            float kw1 = kwbase[(size_t)(r >> 2) * 12288 + t0 + 64 + lane];
            float mn = fmaxf(m[j], fmaxf(s0[j], s1[j]));
            float sc = __expf(m[j] - mn);        // first chunk: exp(-inf)=0
            float p0 = __expf(s0[j] - mn);
            float p1 = __expf(s1[j] - mn);
            den[j] = den[j] * sc + p0 + p1;
            num[j] = num[j] * sc + p0 * kw0 + p1 * kw1;
            m[j] = mn;
        }
    }

#pragma unroll
    for (int j = 0; j < 5; j++) {
        float M = m[j];
#pragma unroll
        for (int off = 32; off; off >>= 1) M = fmaxf(M, __shfl_xor(M, off));
        float sc = __expf(m[j] - M);
        float d = den[j] * sc, n = num[j] * sc;
#pragma unroll
        for (int off = 32; off; off >>= 1) {
            d += __shfl_xor(d, off);
            n += __shfl_xor(n, off);
        }
        if (lane == 0) {
            int r = 5 * w + j;
            atomicAdd(&out[b * 50 + (c0 + (r >> 2))], 0.25f * n / d);
        }
    }
}

extern "C" void kernel_launch(void* const* d_in, const int* in_sizes, int n_in,
                              void* d_out, int out_size, void* d_ws, size_t ws_size,
                              hipStream_t stream) {
    const float* Q    = (const float*)d_in[0];
    const float* H    = (const float*)d_in[1];
    const float* ql   = (const float*)d_in[2];
    const float* WQ_w = (const float*)d_in[3];
    const float* WQ_b = (const float*)d_in[4];
    const float* WK_w = (const float*)d_in[5];
    const float* WK_b = (const float*)d_in[6];
    const float* WV_w = (const float*)d_in[7];
    const float* WV_b = (const float*)d_in[8];
    float* out = (float*)d_out;

    float* ws  = (float*)d_ws;
    float* KS  = ws;                 // 4096*768
    float* QS  = KS + 3145728;       // 200*768
    float* WQL = QS + 153600;        // 50*768
    float* KW  = WQL + 38400;        // 4*50*12*1024
    (void)in_sizes; (void)n_in; (void)out_size; (void)ws_size;

    hipMemsetAsync(d_out, 0, 200 * sizeof(float), stream);

    gemm_bias<true ><<<dim3(12, 64), 128, 0, stream>>>(H, WK_w, WK_b, KS, 4096, 768, 768);
    gemm_bias<false><<<dim3(12, 4), 128, 0, stream>>>(Q, WQ_w, WQ_b, QS, 200, 768, 768);
    gemm_bias<false><<<dim3(12, 1), 128, 0, stream>>>(ql, WV_w, WV_b, WQL, 50, 768, 768);
    kw_kernel<<<768, 256, 0, stream>>>(H, WQL, KW);
    attn2_kernel<<<480, 256, 0, stream>>>(KS, QS, KW, out);
}

// Round 4
// 245.044 us; speedup vs baseline: 1.7465x; 1.7282x over previous
//
#include <hip/hip_runtime.h>
#include <hip/hip_bf16.h>
#include <cmath>

// ---------------------------------------------------------------------------
// MultiSynonymsAttention: c=50 s=4 d=768 b=4 t=1024 z=12 h=64
//   KSb (bf16, [b][z][t][64]) = tanh(H @ WK_w + WK_b)   via bf16 MFMA
//   QS  (f32) = Q @ WQ_w + WQ_b          [200][768]     split-K fp32
//   WQL (f32) = ql @ WV_w + WV_b         [50][768]      split-K fp32
//   KW[b,c,z,t] = sum_h tanh(H[b,t,zh]) * WQL[c,zh]
//   out[b,c] = 0.25 * sum_{z,s} softmax_t(KS.QS) . KW
// ---------------------------------------------------------------------------

typedef __attribute__((ext_vector_type(8))) short bf8_t;    // 8 bf16 = 4 VGPR (MFMA A/B frag)
typedef __attribute__((ext_vector_type(4))) float f32x4;    // MFMA C/D frag
typedef __attribute__((ext_vector_type(4))) short short4v;

__device__ inline unsigned short f2bf(float x) {            // RNE f32->bf16
    unsigned u = __float_as_uint(x);
    return (unsigned short)((u + 0x7fffu + ((u >> 16) & 1u)) >> 16);
}
__device__ inline float bflo(unsigned u) { return __uint_as_float(u << 16); }
__device__ inline float bfhi(unsigned u) { return __uint_as_float(u & 0xffff0000u); }

// ---- WK_w (768x768 f32, [k][n]) -> WT (bf16, [n][k]) ----------------------
__global__ __launch_bounds__(256) void wtrans_kernel(
    const float* __restrict__ W, unsigned short* __restrict__ WT)
{
    __shared__ unsigned short tile[64][72];
    const int bn = blockIdx.x * 64, bk = blockIdx.y * 64;
    const int tid = threadIdx.x;
    const int k = tid >> 4, n4 = (tid & 15) << 2;
#pragma unroll
    for (int i = 0; i < 4; i++) {
        int kk = k + i * 16;
        float4 v = *(const float4*)&W[(size_t)(bk + kk) * 768 + bn + n4];
        tile[n4 + 0][kk] = f2bf(v.x);
        tile[n4 + 1][kk] = f2bf(v.y);
        tile[n4 + 2][kk] = f2bf(v.z);
        tile[n4 + 3][kk] = f2bf(v.w);
    }
    __syncthreads();
#pragma unroll
    for (int i = 0; i < 2; i++) {
        int idx = tid + i * 256;
        int n = idx >> 3, k8 = (idx & 7) << 3;
        bf8_t v = *(const bf8_t*)&tile[n][k8];
        *(bf8_t*)&WT[(size_t)(bn + n) * 768 + bk + k8] = v;
    }
}

// ---- KS = tanh(H @ WK + b) via MFMA; output bf16 [b][z][t][64] ------------
// 256 thr = 4 waves (2x2), tile 64x64, K-step 64.
__global__ __launch_bounds__(256) void ks_mfma_kernel(
    const float* __restrict__ H, const unsigned short* __restrict__ WT,
    const float* __restrict__ bias, unsigned short* __restrict__ KS)
{
    __shared__ unsigned short Al[64][72];   // [m][k]
    __shared__ unsigned short Bl[64][72];   // [n][k]
    const int bn = blockIdx.x * 64;
    const int bm = blockIdx.y * 64;
    const int tid = threadIdx.x;
    const int lane = tid & 63, w = tid >> 6;
    const int wm = (w & 1) * 32, wn = (w >> 1) * 32;
    const int fr = lane & 15, fg = lane >> 4;

    f32x4 acc[2][2] = {};

    for (int k0 = 0; k0 < 768; k0 += 64) {
        // stage A: H 64 rows x 64 k (f32 -> bf16)
#pragma unroll
        for (int i = 0; i < 4; i++) {
            int f = tid + i * 256;
            int r = f >> 4, c4 = (f & 15) << 2;
            float4 v = *(const float4*)&H[(size_t)(bm + r) * 768 + k0 + c4];
            unsigned short tmp[4] = {f2bf(v.x), f2bf(v.y), f2bf(v.z), f2bf(v.w)};
            *(short4v*)&Al[r][c4] = *(const short4v*)tmp;
        }
        // stage B: WT 64 n-rows x 64 k (already bf16)
#pragma unroll
        for (int i = 0; i < 2; i++) {
            int f = tid + i * 256;
            int r = f >> 3, c8 = (f & 7) << 3;
            bf8_t v = *(const bf8_t*)&WT[(size_t)(bn + r) * 768 + k0 + c8];
            *(bf8_t*)&Bl[r][c8] = v;
        }
        __syncthreads();
#pragma unroll
        for (int kk = 0; kk < 2; kk++) {
            bf8_t a0 = *(const bf8_t*)&Al[wm + fr][kk * 32 + fg * 8];
            bf8_t a1 = *(const bf8_t*)&Al[wm + 16 + fr][kk * 32 + fg * 8];
            bf8_t b0 = *(const bf8_t*)&Bl[wn + fr][kk * 32 + fg * 8];
            bf8_t b1 = *(const bf8_t*)&Bl[wn + 16 + fr][kk * 32 + fg * 8];
            acc[0][0] = __builtin_amdgcn_mfma_f32_16x16x32_bf16(a0, b0, acc[0][0], 0, 0, 0);
            acc[0][1] = __builtin_amdgcn_mfma_f32_16x16x32_bf16(a0, b1, acc[0][1], 0, 0, 0);
            acc[1][0] = __builtin_amdgcn_mfma_f32_16x16x32_bf16(a1, b0, acc[1][0], 0, 0, 0);
            acc[1][1] = __builtin_amdgcn_mfma_f32_16x16x32_bf16(a1, b1, acc[1][1], 0, 0, 0);
        }
        __syncthreads();
    }
    // epilogue: C/D layout col=lane&15, row=(lane>>4)*4+reg  [m89/m91]
#pragma unroll
    for (int nt = 0; nt < 2; nt++) {
        int ng = bn + wn + nt * 16 + fr;
        int z = ng >> 6, hh = ng & 63;
        float bv = bias[ng];
#pragma unroll
        for (int mt = 0; mt < 2; mt++) {
#pragma unroll
            for (int r = 0; r < 4; r++) {
                int rg = bm + wm + mt * 16 + fg * 4 + r;
                int bb = rg >> 10, t = rg & 1023;
                float v = tanhf(acc[mt][nt][r] + bv);
                KS[(((size_t)bb * 12 + z) * 1024 + t) * 64 + hh] = f2bf(v);
            }
        }
    }
}

// ---- small fp32 GEMM, split-K with atomic accumulation --------------------
// grid (n/64, ceil(M/64), kchunks); bias added by k-chunk 0.
__global__ __launch_bounds__(128) void gemm_splitk(
    const float* __restrict__ A, const float* __restrict__ B,
    const float* __restrict__ bias, float* __restrict__ C,
    int M, int N, int K, int KC)
{
    __shared__ float As[16][68];
    __shared__ float Bs[16][68];
    const int bm = blockIdx.y * 64, bn = blockIdx.x * 64;
    const int kbeg = blockIdx.z * KC;
    const int tid = threadIdx.x;
    const int row0 = (tid >> 4) << 3;
    const int col0 = (tid & 15) << 2;
    float acc[8][4] = {};

    for (int k0 = kbeg; k0 < kbeg + KC; k0 += 16) {
#pragma unroll
        for (int i = 0; i < 2; i++) {
            int f = tid + i * 128;
            int ar = f >> 2, ak4 = (f & 3) << 2;
            float4 av = make_float4(0.f, 0.f, 0.f, 0.f);
            if (bm + ar < M)
                av = *(const float4*)&A[(size_t)(bm + ar) * K + k0 + ak4];
            As[ak4 + 0][ar] = av.x; As[ak4 + 1][ar] = av.y;
            As[ak4 + 2][ar] = av.z; As[ak4 + 3][ar] = av.w;
        }
#pragma unroll
        for (int i = 0; i < 2; i++) {
            int f = tid + i * 128;
            int bk = f >> 4, bc = (f & 15) << 2;
            float4 bv = *(const float4*)&B[(size_t)(k0 + bk) * N + bn + bc];
            *(float4*)&Bs[bk][bc] = bv;
        }
        __syncthreads();
#pragma unroll
        for (int kk = 0; kk < 16; kk++) {
            float4 b0 = *(const float4*)&Bs[kk][col0];
            float4 a0 = *(const float4*)&As[kk][row0];
            float4 a1 = *(const float4*)&As[kk][row0 + 4];
            float ar8[8] = {a0.x, a0.y, a0.z, a0.w, a1.x, a1.y, a1.z, a1.w};
#pragma unroll
            for (int i = 0; i < 8; i++) {
                acc[i][0] += ar8[i] * b0.x;
                acc[i][1] += ar8[i] * b0.y;
                acc[i][2] += ar8[i] * b0.z;
                acc[i][3] += ar8[i] * b0.w;
            }
        }
        __syncthreads();
    }
    float4 bv = make_float4(0.f, 0.f, 0.f, 0.f);
    if (blockIdx.z == 0) bv = *(const float4*)&bias[bn + col0];
#pragma unroll
    for (int i = 0; i < 8; i++) {
        int row = bm + row0 + i;
        if (row < M) {
            atomicAdd(&C[(size_t)row * N + bn + col0 + 0], acc[i][0] + bv.x);
            atomicAdd(&C[(size_t)row * N + bn + col0 + 1], acc[i][1] + bv.y);
            atomicAdd(&C[(size_t)row * N + bn + col0 + 2], acc[i][2] + bv.z);
            atomicAdd(&C[(size_t)row * N + bn + col0 + 3], acc[i][3] + bv.w);
        }
    }
}

// ---- KW[b,c,z,t] = sum_h tanh(H[b,t,zh]) * WQL[c,zh] ----------------------
// float4 register-blocked: 224 ds_read_b128/thread vs 1664 b32 before.
__global__ __launch_bounds__(256) void kw_kernel2(
    const float* __restrict__ H, const float* __restrict__ WQL,
    float* __restrict__ KW)
{
    const int blk = blockIdx.x;
    const int tchunk = blk & 15;
    const int z = (blk >> 4) % 12;
    const int b = blk / 192;
    const int t0 = tchunk * 64;
    const int tid = threadIdx.x;

    __shared__ float KHs[64][68];
    __shared__ float WQs[50][68];

#pragma unroll
    for (int i = 0; i < 4; i++) {
        int f = tid + i * 256;
        int tt = f >> 4;
        int h4 = (f & 15) << 2;
        float4 v = *(const float4*)&H[((size_t)(b * 1024 + t0 + tt)) * 768 + z * 64 + h4];
        KHs[tt][h4 + 0] = tanhf(v.x);
        KHs[tt][h4 + 1] = tanhf(v.y);
        KHs[tt][h4 + 2] = tanhf(v.z);
        KHs[tt][h4 + 3] = tanhf(v.w);
    }
#pragma unroll
    for (int i = 0; i < 4; i++) {
        int g = tid + i * 256;
        if (g < 800) {
            int cc = g >> 4;
            int h4 = (g & 15) << 2;
            *(float4*)&WQs[cc][h4] = *(const float4*)&WQL[(size_t)cc * 768 + z * 64 + h4];
        }
    }
    __syncthreads();

    const int t = tid & 63;
    const int cg = tid >> 6;                 // wave-uniform
    const int nc = (cg < 2) ? 13 : 12;       // c = cg + 4*i < 50
    float acc[13];
#pragma unroll
    for (int i = 0; i < 13; i++) acc[i] = 0.f;

#pragma unroll
    for (int h4 = 0; h4 < 16; h4++) {
        float4 kh = *(const float4*)&KHs[t][h4 << 2];
#pragma unroll
        for (int i = 0; i < 13; i++) {
            if (i < nc) {
                float4 wq = *(const float4*)&WQs[cg + 4 * i][h4 << 2];
                acc[i] += kh.x * wq.x + kh.y * wq.y + kh.z * wq.z + kh.w * wq.w;
            }
        }
    }
    for (int i = 0; i < nc; i++)
        KW[(((size_t)b * 50 + cg + 4 * i) * 12 + z) * 1024 + t0 + t] = acc[i];
}

// ---- flash attention, bf16 K/Q in LDS, online softmax, scalar num/den -----
// block = (b, z, c-group of 5); 4 waves x 5 rows each.
__global__ __launch_bounds__(256) void attn3_kernel(
    const unsigned short* __restrict__ KS, const float* __restrict__ QS,
    const float* __restrict__ KW, float* __restrict__ out)
{
    const int blk = blockIdx.x;
    const int cg = blk % 10;
    const int z  = (blk / 10) % 12;
    const int b  = blk / 120;
    const int c0 = cg * 5;
    const int tid = threadIdx.x;
    const int lane = tid & 63;
    const int w = tid >> 6;

    __shared__ unsigned short Kl[128][72];   // 18.4 KB, pad-72: optimal b128 banks
    __shared__ unsigned short ql_[20][72];

    for (int f = tid; f < 320; f += 256) {
        int r = f >> 4, s4 = (f & 15) << 2;
        float4 v = *(const float4*)&QS[(size_t)(c0 * 4 + r) * 768 + z * 64 + s4];
        unsigned short tmp[4] = {f2bf(v.x), f2bf(v.y), f2bf(v.z), f2bf(v.w)};
        *(short4v*)&ql_[r][s4] = *(const short4v*)tmp;
    }

    float m[5], den[5], num[5];
#pragma unroll
    for (int j = 0; j < 5; j++) { m[j] = -INFINITY; den[j] = 0.f; num[j] = 0.f; }

    const float* kwbase = &KW[(((size_t)b * 50 + c0) * 12 + z) * 1024];
    const unsigned short* ksbase = &KS[((size_t)(b * 12 + z) * 1024) * 64];

    for (int t0 = 0; t0 < 1024; t0 += 128) {
        __syncthreads();
#pragma unroll
        for (int i = 0; i < 4; i++) {
            int idx = tid + i * 256;
            int row = idx >> 3, c8 = (idx & 7) << 3;
            bf8_t v = *(const bf8_t*)&ksbase[(size_t)(t0 + row) * 64 + c8];
            *(bf8_t*)&Kl[row][c8] = v;
        }
        __syncthreads();

        float s0[5] = {0.f, 0.f, 0.f, 0.f, 0.f};
        float s1[5] = {0.f, 0.f, 0.f, 0.f, 0.f};
#pragma unroll
        for (int h8 = 0; h8 < 8; h8++) {
            uint4 k0v = *(const uint4*)&Kl[lane][h8 << 3];
            uint4 k1v = *(const uint4*)&Kl[lane + 64][h8 << 3];
            float k0f[8] = {bflo(k0v.x), bfhi(k0v.x), bflo(k0v.y), bfhi(k0v.y),
                            bflo(k0v.z), bfhi(k0v.z), bflo(k0v.w), bfhi(k0v.w)};
            float k1f[8] = {bflo(k1v.x), bfhi(k1v.x), bflo(k1v.y), bfhi(k1v.y),
                            bflo(k1v.z), bfhi(k1v.z), bflo(k1v.w), bfhi(k1v.w)};
#pragma unroll
            for (int j = 0; j < 5; j++) {
                uint4 qv = *(const uint4*)&ql_[5 * w + j][h8 << 3];
                float q0 = bflo(qv.x), q1 = bfhi(qv.x), q2 = bflo(qv.y), q3 = bfhi(qv.y);
                float q4 = bflo(qv.z), q5 = bfhi(qv.z), q6 = bflo(qv.w), q7 = bfhi(qv.w);
                s0[j] += k0f[0] * q0 + k0f[1] * q1 + k0f[2] * q2 + k0f[3] * q3
                       + k0f[4] * q4 + k0f[5] * q5 + k0f[6] * q6 + k0f[7] * q7;
                s1[j] += k1f[0] * q0 + k1f[1] * q1 + k1f[2] * q2 + k1f[3] * q3
                       + k1f[4] * q4 + k1f[5] * q5 + k1f[6] * q6 + k1f[7] * q7;
            }
        }
#pragma unroll
        for (int j = 0; j < 5; j++) {
            int r = 5 * w + j;
            float kw0 = kwbase[(size_t)(r >> 2) * 12288 + t0 + lane];
            float kw1 = kwbase[(size_t)(r >> 2) * 12288 + t0 + 64 + lane];
            float mn = fmaxf(m[j], fmaxf(s0[j], s1[j]));
            float sc = __expf(m[j] - mn);
            float p0 = __expf(s0[j] - mn);
            float p1 = __expf(s1[j] - mn);
            den[j] = den[j] * sc + p0 + p1;
            num[j] = num[j] * sc + p0 * kw0 + p1 * kw1;
            m[j] = mn;
        }
    }

#pragma unroll
    for (int j = 0; j < 5; j++) {
        float M = m[j];
#pragma unroll
        for (int off = 32; off; off >>= 1) M = fmaxf(M, __shfl_xor(M, off));
        float sc = __expf(m[j] - M);
        float d = den[j] * sc, n = num[j] * sc;
#pragma unroll
        for (int off = 32; off; off >>= 1) {
            d += __shfl_xor(d, off);
            n += __shfl_xor(n, off);
        }
        if (lane == 0) {
            int r = 5 * w + j;
            atomicAdd(&out[b * 50 + (c0 + (r >> 2))], 0.25f * n / d);
        }
    }
}

extern "C" void kernel_launch(void* const* d_in, const int* in_sizes, int n_in,
                              void* d_out, int out_size, void* d_ws, size_t ws_size,
                              hipStream_t stream) {
    const float* Q    = (const float*)d_in[0];
    const float* H    = (const float*)d_in[1];
    const float* ql   = (const float*)d_in[2];
    const float* WQ_w = (const float*)d_in[3];
    const float* WQ_b = (const float*)d_in[4];
    const float* WK_w = (const float*)d_in[5];
    const float* WK_b = (const float*)d_in[6];
    const float* WV_w = (const float*)d_in[7];
    const float* WV_b = (const float*)d_in[8];
    float* out = (float*)d_out;

    float* ws = (float*)d_ws;
    unsigned short* KSb = (unsigned short*)ws;                     // 3,145,728 bf16
    unsigned short* WT  = (unsigned short*)(ws + 1572864);         //   589,824 bf16
    float* QS  = ws + 1572864 + 294912;                            //   153,600 f32
    float* WQL = QS + 153600;                                      //    38,400 f32
    float* KW  = WQL + 38400;                                      // 2,457,600 f32
    (void)in_sizes; (void)n_in; (void)out_size; (void)ws_size;

    hipMemsetAsync(d_out, 0, 200 * sizeof(float), stream);
    hipMemsetAsync(QS, 0, 153600 * sizeof(float), stream);
    hipMemsetAsync(WQL, 0, 38400 * sizeof(float), stream);

    wtrans_kernel<<<dim3(12, 12), 256, 0, stream>>>(WK_w, WT);
    ks_mfma_kernel<<<dim3(12, 64), 256, 0, stream>>>(H, WT, WK_b, KSb);
    gemm_splitk<<<dim3(12, 4, 4), 128, 0, stream>>>(Q, WQ_w, WQ_b, QS, 200, 768, 768, 192);
    gemm_splitk<<<dim3(12, 1, 6), 128, 0, stream>>>(ql, WV_w, WV_b, WQL, 50, 768, 768, 128);
    kw_kernel2<<<768, 256, 0, stream>>>(H, WQL, KW);
    attn3_kernel<<<480, 256, 0, stream>>>(KSb, QS, KW, out);
}

// Round 5
// 225.836 us; speedup vs baseline: 1.8950x; 1.0851x over previous
//
#include <hip/hip_runtime.h>
#include <hip/hip_bf16.h>
#include <cmath>

// ---------------------------------------------------------------------------
// MultiSynonymsAttention: c=50 s=4 d=768 b=4 t=1024 z=12 h=64
//   Hbf (bf16)  = bf16(H)                              [4096][768] (aliases KW)
//   KSb (bf16, [b][z][t][64]) = tanh(H @ WK_w + WK_b)  via bf16 MFMA
//   QS  (f32) = Q @ WQ_w + WQ_b          [200][768]    split-K fp32
//   WQL (f32) = ql @ WV_w + WV_b         [50][768]     split-K fp32
//   KW[b,c,z,t] = sum_h tanh(H[b,t,zh]) * WQL[c,zh]
//   out[b,c] = 0.25 * sum_{z,s} softmax_t(KS.QS) . KW   (t-split x4 + reduce)
// ---------------------------------------------------------------------------

typedef __attribute__((ext_vector_type(8))) short bf8_t;
typedef __attribute__((ext_vector_type(4))) float f32x4;
typedef __attribute__((ext_vector_type(4))) short short4v;

__device__ inline unsigned short f2bf(float x) {            // RNE f32->bf16
    unsigned u = __float_as_uint(x);
    return (unsigned short)((u + 0x7fffu + ((u >> 16) & 1u)) >> 16);
}
__device__ inline float bflo(unsigned u) { return __uint_as_float(u << 16); }
__device__ inline float bfhi(unsigned u) { return __uint_as_float(u & 0xffff0000u); }

// ---- H (f32) -> Hbf (bf16), 8 elems/thread --------------------------------
__global__ __launch_bounds__(256) void hbf_kernel(
    const float* __restrict__ H, unsigned short* __restrict__ Hb)
{
    int i = (blockIdx.x * 256 + threadIdx.x) * 8;
    float4 v0 = *(const float4*)&H[i];
    float4 v1 = *(const float4*)&H[i + 4];
    unsigned short t[8] = {f2bf(v0.x), f2bf(v0.y), f2bf(v0.z), f2bf(v0.w),
                           f2bf(v1.x), f2bf(v1.y), f2bf(v1.z), f2bf(v1.w)};
    *(bf8_t*)&Hb[i] = *(const bf8_t*)t;
}

// ---- WK_w (768x768 f32, [k][n]) -> WT (bf16, [n][k]) ----------------------
__global__ __launch_bounds__(256) void wtrans_kernel(
    const float* __restrict__ W, unsigned short* __restrict__ WT)
{
    __shared__ unsigned short tile[64][72];
    const int bn = blockIdx.x * 64, bk = blockIdx.y * 64;
    const int tid = threadIdx.x;
    const int k = tid >> 4, n4 = (tid & 15) << 2;
#pragma unroll
    for (int i = 0; i < 4; i++) {
        int kk = k + i * 16;
        float4 v = *(const float4*)&W[(size_t)(bk + kk) * 768 + bn + n4];
        tile[n4 + 0][kk] = f2bf(v.x);
        tile[n4 + 1][kk] = f2bf(v.y);
        tile[n4 + 2][kk] = f2bf(v.z);
        tile[n4 + 3][kk] = f2bf(v.w);
    }
    __syncthreads();
#pragma unroll
    for (int i = 0; i < 2; i++) {
        int idx = tid + i * 256;
        int n = idx >> 3, k8 = (idx & 7) << 3;
        bf8_t v = *(const bf8_t*)&tile[n][k8];
        *(bf8_t*)&WT[(size_t)(bn + n) * 768 + bk + k8] = v;
    }
}

// ---- KS = tanh(Hbf @ WT^T + b) via MFMA; out bf16 [b][z][t][64] -----------
// 128x64 tile, K-step 64, 256 thr = 4 waves (2 M x 2 N), wave = 64x32.
__global__ __launch_bounds__(256) void ks_mfma2_kernel(
    const unsigned short* __restrict__ Hb, const unsigned short* __restrict__ WT,
    const float* __restrict__ bias, unsigned short* __restrict__ KS)
{
    __shared__ unsigned short Al[128][72];   // [m][k]
    __shared__ unsigned short Bl[64][72];    // [n][k]
    const int z  = blockIdx.x;               // bn = z*64: block is one head
    const int bm = blockIdx.y * 128;
    const int bn = z * 64;
    const int tid = threadIdx.x;
    const int lane = tid & 63, w = tid >> 6;
    const int wm = (w & 1) * 64, wn = (w >> 1) * 32;
    const int fr = lane & 15, fg = lane >> 4;

    f32x4 acc[4][2] = {};

    for (int k0 = 0; k0 < 768; k0 += 64) {
#pragma unroll
        for (int i = 0; i < 4; i++) {
            int f = tid + i * 256;
            int r = f >> 3, c8 = (f & 7) << 3;
            *(bf8_t*)&Al[r][c8] = *(const bf8_t*)&Hb[(size_t)(bm + r) * 768 + k0 + c8];
        }
#pragma unroll
        for (int i = 0; i < 2; i++) {
            int f = tid + i * 256;
            int r = f >> 3, c8 = (f & 7) << 3;
            *(bf8_t*)&Bl[r][c8] = *(const bf8_t*)&WT[(size_t)(bn + r) * 768 + k0 + c8];
        }
        __syncthreads();
#pragma unroll
        for (int kk = 0; kk < 2; kk++) {
            bf8_t a[4], bb[2];
#pragma unroll
            for (int mt = 0; mt < 4; mt++)
                a[mt] = *(const bf8_t*)&Al[wm + mt * 16 + fr][kk * 32 + fg * 8];
#pragma unroll
            for (int nt = 0; nt < 2; nt++)
                bb[nt] = *(const bf8_t*)&Bl[wn + nt * 16 + fr][kk * 32 + fg * 8];
#pragma unroll
            for (int mt = 0; mt < 4; mt++)
#pragma unroll
                for (int nt = 0; nt < 2; nt++)
                    acc[mt][nt] = __builtin_amdgcn_mfma_f32_16x16x32_bf16(
                        a[mt], bb[nt], acc[mt][nt], 0, 0, 0);
        }
        __syncthreads();
    }
    // C/D layout: col=lane&15, row=(lane>>4)*4+reg
#pragma unroll
    for (int nt = 0; nt < 2; nt++) {
        int ng = bn + wn + nt * 16 + fr;
        int hh = ng & 63;
        float bv = bias[ng];
#pragma unroll
        for (int mt = 0; mt < 4; mt++) {
#pragma unroll
            for (int r = 0; r < 4; r++) {
                int rg = bm + wm + mt * 16 + fg * 4 + r;
                int bb2 = rg >> 10, t = rg & 1023;
                KS[(((size_t)bb2 * 12 + z) * 1024 + t) * 64 + hh] =
                    f2bf(tanhf(acc[mt][nt][r] + bv));
            }
        }
    }
}

// ---- small fp32 GEMM, split-K with atomic accumulation --------------------
__global__ __launch_bounds__(128) void gemm_splitk(
    const float* __restrict__ A, const float* __restrict__ B,
    const float* __restrict__ bias, float* __restrict__ C,
    int M, int N, int K, int KC)
{
    __shared__ float As[16][68];
    __shared__ float Bs[16][68];
    const int bm = blockIdx.y * 64, bn = blockIdx.x * 64;
    const int kbeg = blockIdx.z * KC;
    const int tid = threadIdx.x;
    const int row0 = (tid >> 4) << 3;
    const int col0 = (tid & 15) << 2;
    float acc[8][4] = {};

    for (int k0 = kbeg; k0 < kbeg + KC; k0 += 16) {
#pragma unroll
        for (int i = 0; i < 2; i++) {
            int f = tid + i * 128;
            int ar = f >> 2, ak4 = (f & 3) << 2;
            float4 av = make_float4(0.f, 0.f, 0.f, 0.f);
            if (bm + ar < M)
                av = *(const float4*)&A[(size_t)(bm + ar) * K + k0 + ak4];
            As[ak4 + 0][ar] = av.x; As[ak4 + 1][ar] = av.y;
            As[ak4 + 2][ar] = av.z; As[ak4 + 3][ar] = av.w;
        }
#pragma unroll
        for (int i = 0; i < 2; i++) {
            int f = tid + i * 128;
            int bk = f >> 4, bc = (f & 15) << 2;
            float4 bv = *(const float4*)&B[(size_t)(k0 + bk) * N + bn + bc];
            *(float4*)&Bs[bk][bc] = bv;
        }
        __syncthreads();
#pragma unroll
        for (int kk = 0; kk < 16; kk++) {
            float4 b0 = *(const float4*)&Bs[kk][col0];
            float4 a0 = *(const float4*)&As[kk][row0];
            float4 a1 = *(const float4*)&As[kk][row0 + 4];
            float ar8[8] = {a0.x, a0.y, a0.z, a0.w, a1.x, a1.y, a1.z, a1.w};
#pragma unroll
            for (int i = 0; i < 8; i++) {
                acc[i][0] += ar8[i] * b0.x;
                acc[i][1] += ar8[i] * b0.y;
                acc[i][2] += ar8[i] * b0.z;
                acc[i][3] += ar8[i] * b0.w;
            }
        }
        __syncthreads();
    }
    float4 bv = make_float4(0.f, 0.f, 0.f, 0.f);
    if (blockIdx.z == 0) bv = *(const float4*)&bias[bn + col0];
#pragma unroll
    for (int i = 0; i < 8; i++) {
        int row = bm + row0 + i;
        if (row < M) {
            atomicAdd(&C[(size_t)row * N + bn + col0 + 0], acc[i][0] + bv.x);
            atomicAdd(&C[(size_t)row * N + bn + col0 + 1], acc[i][1] + bv.y);
            atomicAdd(&C[(size_t)row * N + bn + col0 + 2], acc[i][2] + bv.z);
            atomicAdd(&C[(size_t)row * N + bn + col0 + 3], acc[i][3] + bv.w);
        }
    }
}

// ---- KW[b,c,z,t] = sum_h tanh(H[b,t,zh]) * WQL[c,zh] ----------------------
__global__ __launch_bounds__(256) void kw_kernel2(
    const float* __restrict__ H, const float* __restrict__ WQL,
    float* __restrict__ KW)
{
    const int blk = blockIdx.x;
    const int tchunk = blk & 15;
    const int z = (blk >> 4) % 12;
    const int b = blk / 192;
    const int t0 = tchunk * 64;
    const int tid = threadIdx.x;

    __shared__ float KHs[64][68];
    __shared__ float WQs[50][68];

#pragma unroll
    for (int i = 0; i < 4; i++) {
        int f = tid + i * 256;
        int tt = f >> 4;
        int h4 = (f & 15) << 2;
        float4 v = *(const float4*)&H[((size_t)(b * 1024 + t0 + tt)) * 768 + z * 64 + h4];
        KHs[tt][h4 + 0] = tanhf(v.x);
        KHs[tt][h4 + 1] = tanhf(v.y);
        KHs[tt][h4 + 2] = tanhf(v.z);
        KHs[tt][h4 + 3] = tanhf(v.w);
    }
#pragma unroll
    for (int i = 0; i < 4; i++) {
        int g = tid + i * 256;
        if (g < 800) {
            int cc = g >> 4;
            int h4 = (g & 15) << 2;
            *(float4*)&WQs[cc][h4] = *(const float4*)&WQL[(size_t)cc * 768 + z * 64 + h4];
        }
    }
    __syncthreads();

    const int t = tid & 63;
    const int cg = tid >> 6;
    const int nc = (cg < 2) ? 13 : 12;
    float acc[13];
#pragma unroll
    for (int i = 0; i < 13; i++) acc[i] = 0.f;

#pragma unroll
    for (int h4 = 0; h4 < 16; h4++) {
        float4 kh = *(const float4*)&KHs[t][h4 << 2];
#pragma unroll
        for (int i = 0; i < 13; i++) {
            if (i < nc) {
                float4 wq = *(const float4*)&WQs[cg + 4 * i][h4 << 2];
                acc[i] += kh.x * wq.x + kh.y * wq.y + kh.z * wq.z + kh.w * wq.w;
            }
        }
    }
    for (int i = 0; i < nc; i++)
        KW[(((size_t)b * 50 + cg + 4 * i) * 12 + z) * 1024 + t0 + t] = acc[i];
}

// ---- flash attention, t-split x4: partial (m,den,num) per row -------------
// block = (ts, b, z, cgroup); 4 waves x 5 rows; each block covers 256 t.
__global__ __launch_bounds__(256) void attn4_kernel(
    const unsigned short* __restrict__ KS, const float* __restrict__ QS,
    const float* __restrict__ KW,
    float* __restrict__ pm, float* __restrict__ pd, float* __restrict__ pn)
{
    const int blk = blockIdx.x;
    const int cg = blk % 10;
    const int z  = (blk / 10) % 12;
    const int b  = (blk / 120) % 4;
    const int ts = blk / 480;
    const int c0 = cg * 5;
    const int tid = threadIdx.x;
    const int lane = tid & 63;
    const int w = tid >> 6;

    __shared__ unsigned short Kl[128][72];
    __shared__ unsigned short ql_[20][72];

    for (int f = tid; f < 320; f += 256) {
        int r = f >> 4, s4 = (f & 15) << 2;
        float4 v = *(const float4*)&QS[(size_t)(c0 * 4 + r) * 768 + z * 64 + s4];
        unsigned short tmp[4] = {f2bf(v.x), f2bf(v.y), f2bf(v.z), f2bf(v.w)};
        *(short4v*)&ql_[r][s4] = *(const short4v*)tmp;
    }

    float m[5], den[5], num[5];
#pragma unroll
    for (int j = 0; j < 5; j++) { m[j] = -INFINITY; den[j] = 0.f; num[j] = 0.f; }

    const float* kwbase = &KW[(((size_t)b * 50 + c0) * 12 + z) * 1024];
    const unsigned short* ksbase = &KS[((size_t)(b * 12 + z) * 1024) * 64];

    for (int t0 = ts * 256; t0 < ts * 256 + 256; t0 += 128) {
        __syncthreads();
#pragma unroll
        for (int i = 0; i < 4; i++) {
            int idx = tid + i * 256;
            int row = idx >> 3, c8 = (idx & 7) << 3;
            bf8_t v = *(const bf8_t*)&ksbase[(size_t)(t0 + row) * 64 + c8];
            *(bf8_t*)&Kl[row][c8] = v;
        }
        __syncthreads();

        float s0[5] = {0.f, 0.f, 0.f, 0.f, 0.f};
        float s1[5] = {0.f, 0.f, 0.f, 0.f, 0.f};
#pragma unroll
        for (int h8 = 0; h8 < 8; h8++) {
            uint4 k0v = *(const uint4*)&Kl[lane][h8 << 3];
            uint4 k1v = *(const uint4*)&Kl[lane + 64][h8 << 3];
            float k0f[8] = {bflo(k0v.x), bfhi(k0v.x), bflo(k0v.y), bfhi(k0v.y),
                            bflo(k0v.z), bfhi(k0v.z), bflo(k0v.w), bfhi(k0v.w)};
            float k1f[8] = {bflo(k1v.x), bfhi(k1v.x), bflo(k1v.y), bfhi(k1v.y),
                            bflo(k1v.z), bfhi(k1v.z), bflo(k1v.w), bfhi(k1v.w)};
#pragma unroll
            for (int j = 0; j < 5; j++) {
                uint4 qv = *(const uint4*)&ql_[5 * w + j][h8 << 3];
                float q0 = bflo(qv.x), q1 = bfhi(qv.x), q2 = bflo(qv.y), q3 = bfhi(qv.y);
                float q4 = bflo(qv.z), q5 = bfhi(qv.z), q6 = bflo(qv.w), q7 = bfhi(qv.w);
                s0[j] += k0f[0] * q0 + k0f[1] * q1 + k0f[2] * q2 + k0f[3] * q3
                       + k0f[4] * q4 + k0f[5] * q5 + k0f[6] * q6 + k0f[7] * q7;
                s1[j] += k1f[0] * q0 + k1f[1] * q1 + k1f[2] * q2 + k1f[3] * q3
                       + k1f[4] * q4 + k1f[5] * q5 + k1f[6] * q6 + k1f[7] * q7;
            }
        }
#pragma unroll
        for (int j = 0; j < 5; j++) {
            int r = 5 * w + j;
            float kw0 = kwbase[(size_t)(r >> 2) * 12288 + t0 + lane];
            float kw1 = kwbase[(size_t)(r >> 2) * 12288 + t0 + 64 + lane];
            float mn = fmaxf(m[j], fmaxf(s0[j], s1[j]));
            float sc = __expf(m[j] - mn);
            float p0 = __expf(s0[j] - mn);
            float p1 = __expf(s1[j] - mn);
            den[j] = den[j] * sc + p0 + p1;
            num[j] = num[j] * sc + p0 * kw0 + p1 * kw1;
            m[j] = mn;
        }
    }

#pragma unroll
    for (int j = 0; j < 5; j++) {
        float M = m[j];
#pragma unroll
        for (int off = 32; off; off >>= 1) M = fmaxf(M, __shfl_xor(M, off));
        float sc = __expf(m[j] - M);
        float d = den[j] * sc, n = num[j] * sc;
#pragma unroll
        for (int off = 32; off; off >>= 1) {
            d += __shfl_xor(d, off);
            n += __shfl_xor(n, off);
        }
        if (lane == 0) {
            int R = ((b * 10 + cg) * 12 + z) * 20 + w * 5 + j;
            pm[R * 4 + ts] = M;
            pd[R * 4 + ts] = d;
            pn[R * 4 + ts] = n;
        }
    }
}

// ---- merge 4 t-partials per row, atomicAdd into out -----------------------
__global__ __launch_bounds__(256) void attn_reduce_kernel(
    const float* __restrict__ pm, const float* __restrict__ pd,
    const float* __restrict__ pn, float* __restrict__ out)
{
    int R = blockIdx.x * 256 + threadIdx.x;
    if (R >= 9600) return;
    float M = -INFINITY;
#pragma unroll
    for (int i = 0; i < 4; i++) M = fmaxf(M, pm[R * 4 + i]);
    float D = 0.f, Nn = 0.f;
#pragma unroll
    for (int i = 0; i < 4; i++) {
        float e = __expf(pm[R * 4 + i] - M);
        D  += pd[R * 4 + i] * e;
        Nn += pn[R * 4 + i] * e;
    }
    int rr = R % 20;
    int q  = R / 20;
    int q2 = q / 12;             // z = q % 12 (unused)
    int cg = q2 % 10, b = q2 / 10;
    int c = cg * 5 + (rr >> 2);
    atomicAdd(&out[b * 50 + c], 0.25f * Nn / D);
}

extern "C" void kernel_launch(void* const* d_in, const int* in_sizes, int n_in,
                              void* d_out, int out_size, void* d_ws, size_t ws_size,
                              hipStream_t stream) {
    const float* Q    = (const float*)d_in[0];
    const float* H    = (const float*)d_in[1];
    const float* ql   = (const float*)d_in[2];
    const float* WQ_w = (const float*)d_in[3];
    const float* WQ_b = (const float*)d_in[4];
    const float* WK_w = (const float*)d_in[5];
    const float* WK_b = (const float*)d_in[6];
    const float* WV_w = (const float*)d_in[7];
    const float* WV_b = (const float*)d_in[8];
    float* out = (float*)d_out;

    float* ws = (float*)d_ws;
    unsigned short* KSb = (unsigned short*)ws;               // 3,145,728 bf16
    unsigned short* WT  = (unsigned short*)(ws + 1572864);   //   589,824 bf16
    float* QS  = ws + 1572864 + 294912;                      //   153,600 f32
    float* WQL = QS + 153600;                                //    38,400 f32
    float* KW  = WQL + 38400;                                // 2,457,600 f32
    unsigned short* Hbf = (unsigned short*)KW;               // aliases KW (dead before kw2)
    float* pm  = KW + 2457600;                               //    38,400 f32
    float* pd  = pm + 38400;
    float* pn  = pd + 38400;
    (void)in_sizes; (void)n_in; (void)out_size; (void)ws_size;

    hipMemsetAsync(d_out, 0, 200 * sizeof(float), stream);
    hipMemsetAsync(QS, 0, 192000 * sizeof(float), stream);   // QS + WQL contiguous

    wtrans_kernel<<<dim3(12, 12), 256, 0, stream>>>(WK_w, WT);
    hbf_kernel<<<1536, 256, 0, stream>>>(H, Hbf);
    ks_mfma2_kernel<<<dim3(12, 32), 256, 0, stream>>>(Hbf, WT, WK_b, KSb);
    gemm_splitk<<<dim3(12, 4, 4), 128, 0, stream>>>(Q, WQ_w, WQ_b, QS, 200, 768, 768, 192);
    gemm_splitk<<<dim3(12, 1, 6), 128, 0, stream>>>(ql, WV_w, WV_b, WQL, 50, 768, 768, 128);
    kw_kernel2<<<768, 256, 0, stream>>>(H, WQL, KW);         // overwrites Hbf (done)
    attn4_kernel<<<1920, 256, 0, stream>>>(KSb, QS, KW, pm, pd, pn);
    attn_reduce_kernel<<<38, 256, 0, stream>>>(pm, pd, pn, out);
}

// Round 6
// 152.726 us; speedup vs baseline: 2.8022x; 1.4787x over previous
//
#include <hip/hip_runtime.h>
#include <hip/hip_bf16.h>
#include <cmath>

// ---------------------------------------------------------------------------
// MultiSynonymsAttention: c=50 s=4 d=768 b=4 t=1024 z=12 h=64
// Pipeline (6 launches, all MFMA for matmul-shaped work):
//  prep    : Hbf=bf16(H), THbf=bf16(ftanh(H)), WTk/q/v = bf16(W^T), Qbf, qlbf
//  gemm_all: job0 KSb = bf16(ftanh(Hbf@WTk^T + bk))   [b][z][t][64]
//            job1 QSbf = bf16(Qbf@WTq^T + bq)         [208][768]
//            job2 WQLbf = bf16(qlbf@WTv^T + bv)       [64][768]
//  kw_mfma : KW[b,c,z,t] = THbf_z @ WQLbf_z^T         f32 [b][c][z][1024]
//  attn5   : scores via MFMA (A=KS rows t, B=QS rows cs), online softmax
//            over t per lane, fg-merge, t-split x8 partials (m,den,num)
//  reduce  : merge 8 partials/row, atomicAdd 0.25*num/den into out[b,c]
// ---------------------------------------------------------------------------

typedef __attribute__((ext_vector_type(8))) short bf8_t;
typedef __attribute__((ext_vector_type(4))) float f32x4;

__device__ inline unsigned short f2bf(float x) {            // RNE f32->bf16
    unsigned u = __float_as_uint(x);
    return (unsigned short)((u + 0x7fffu + ((u >> 16) & 1u)) >> 16);
}
__device__ inline float ftanh(float x) {                    // 1 - 2/(e^2x+1)
    float t = __expf(2.f * x);                              // +inf ok -> 1
    return 1.f - 2.f * __builtin_amdgcn_rcpf(t + 1.f);      // -inf -> -1
}

// ---- prep: all input conversions in one launch ----------------------------
// blocks [0,1536): H -> Hbf + THbf      (4096*768 / 2048 per block)
// [1536,1968): W^T -> bf16 (3 x 144)    (WK, WQ, WV)
// [1968,2043): Q -> Qbf                 (200*768)
// [2043,2062): ql -> qlbf               (50*768, guarded)
__global__ __launch_bounds__(256) void prep_kernel(
    const float* __restrict__ H, const float* __restrict__ WK,
    const float* __restrict__ WQ, const float* __restrict__ WV,
    const float* __restrict__ Q, const float* __restrict__ ql,
    unsigned short* __restrict__ Hbf, unsigned short* __restrict__ THbf,
    unsigned short* __restrict__ WTk, unsigned short* __restrict__ WTq,
    unsigned short* __restrict__ WTv,
    unsigned short* __restrict__ Qbf, unsigned short* __restrict__ qlbf)
{
    __shared__ unsigned short tile[64][72];
    const int bid = blockIdx.x, tid = threadIdx.x;
    if (bid < 1536) {
        int i = (bid * 256 + tid) * 8;
        float4 v0 = *(const float4*)&H[i];
        float4 v1 = *(const float4*)&H[i + 4];
        unsigned short h8[8] = {f2bf(v0.x), f2bf(v0.y), f2bf(v0.z), f2bf(v0.w),
                                f2bf(v1.x), f2bf(v1.y), f2bf(v1.z), f2bf(v1.w)};
        *(bf8_t*)&Hbf[i] = *(const bf8_t*)h8;
        unsigned short t8[8] = {f2bf(ftanh(v0.x)), f2bf(ftanh(v0.y)),
                                f2bf(ftanh(v0.z)), f2bf(ftanh(v0.w)),
                                f2bf(ftanh(v1.x)), f2bf(ftanh(v1.y)),
                                f2bf(ftanh(v1.z)), f2bf(ftanh(v1.w))};
        *(bf8_t*)&THbf[i] = *(const bf8_t*)t8;
    } else if (bid < 1968) {
        int j = bid - 1536;
        int wsel = j / 144, l = j % 144;
        const float* W = (wsel == 0) ? WK : (wsel == 1) ? WQ : WV;
        unsigned short* WT = (wsel == 0) ? WTk : (wsel == 1) ? WTq : WTv;
        const int bn = (l % 12) * 64, bk = (l / 12) * 64;
        const int k = tid >> 4, n4 = (tid & 15) << 2;
#pragma unroll
        for (int i = 0; i < 4; i++) {
            int kk = k + i * 16;
            float4 v = *(const float4*)&W[(size_t)(bk + kk) * 768 + bn + n4];
            tile[n4 + 0][kk] = f2bf(v.x);
            tile[n4 + 1][kk] = f2bf(v.y);
            tile[n4 + 2][kk] = f2bf(v.z);
            tile[n4 + 3][kk] = f2bf(v.w);
        }
        __syncthreads();
#pragma unroll
        for (int i = 0; i < 2; i++) {
            int idx = tid + i * 256;
            int n = idx >> 3, k8 = (idx & 7) << 3;
            *(bf8_t*)&WT[(size_t)(bn + n) * 768 + bk + k8] = *(const bf8_t*)&tile[n][k8];
        }
    } else if (bid < 2043) {
        int i = ((bid - 1968) * 256 + tid) * 8;
        float4 v0 = *(const float4*)&Q[i];
        float4 v1 = *(const float4*)&Q[i + 4];
        unsigned short h8[8] = {f2bf(v0.x), f2bf(v0.y), f2bf(v0.z), f2bf(v0.w),
                                f2bf(v1.x), f2bf(v1.y), f2bf(v1.z), f2bf(v1.w)};
        *(bf8_t*)&Qbf[i] = *(const bf8_t*)h8;
    } else {
        int i = ((bid - 2043) * 256 + tid) * 8;
        if (i < 38400) {
            float4 v0 = *(const float4*)&ql[i];
            float4 v1 = *(const float4*)&ql[i + 4];
            unsigned short h8[8] = {f2bf(v0.x), f2bf(v0.y), f2bf(v0.z), f2bf(v0.w),
                                    f2bf(v1.x), f2bf(v1.y), f2bf(v1.z), f2bf(v1.w)};
            *(bf8_t*)&qlbf[i] = *(const bf8_t*)h8;
        }
    }
}

// ---- unified bf16 MFMA GEMM: 128x64 tile, K=768, 3 job types --------------
// bid [0,384): job0 KS; [384,408): job1 QS; [408,420): job2 WQL.
__global__ __launch_bounds__(256) void gemm_all_kernel(
    const unsigned short* __restrict__ Hbf, const unsigned short* __restrict__ Qbf,
    const unsigned short* __restrict__ qlbf,
    const unsigned short* __restrict__ WTk, const unsigned short* __restrict__ WTq,
    const unsigned short* __restrict__ WTv,
    const float* __restrict__ bk, const float* __restrict__ bq,
    const float* __restrict__ bv,
    unsigned short* __restrict__ KSb, unsigned short* __restrict__ QSbf,
    unsigned short* __restrict__ WQLbf)
{
    __shared__ unsigned short Al[128][72];
    __shared__ unsigned short Bl[64][72];
    const int bid = blockIdx.x, tid = threadIdx.x;
    int job, bm, bn, Mr, z = 0;
    const unsigned short *A, *B;
    const float* bias;
    if (bid < 384) {
        job = 0; z = bid % 12; bm = (bid / 12) * 128; bn = z * 64;
        A = Hbf; B = WTk; bias = bk; Mr = 4096;
    } else if (bid < 408) {
        int l = bid - 384;
        job = 1; bm = (l / 12) * 128; bn = (l % 12) * 64;
        A = Qbf; B = WTq; bias = bq; Mr = 200;
    } else {
        job = 2; bm = 0; bn = (bid - 408) * 64;
        A = qlbf; B = WTv; bias = bv; Mr = 50;
    }
    const int lane = tid & 63, w = tid >> 6;
    const int wm = (w & 1) * 64, wn = (w >> 1) * 32;
    const int fr = lane & 15, fg = lane >> 4;

    f32x4 acc[4][2] = {};

    for (int k0 = 0; k0 < 768; k0 += 64) {
#pragma unroll
        for (int i = 0; i < 4; i++) {
            int f = tid + i * 256;
            int r = f >> 3, c8 = (f & 7) << 3;
            bf8_t v = {};
            if (bm + r < Mr)
                v = *(const bf8_t*)&A[(size_t)(bm + r) * 768 + k0 + c8];
            *(bf8_t*)&Al[r][c8] = v;
        }
#pragma unroll
        for (int i = 0; i < 2; i++) {
            int f = tid + i * 256;
            int r = f >> 3, c8 = (f & 7) << 3;
            *(bf8_t*)&Bl[r][c8] = *(const bf8_t*)&B[(size_t)(bn + r) * 768 + k0 + c8];
        }
        __syncthreads();
#pragma unroll
        for (int kk = 0; kk < 2; kk++) {
            bf8_t a[4], bb[2];
#pragma unroll
            for (int mt = 0; mt < 4; mt++)
                a[mt] = *(const bf8_t*)&Al[wm + mt * 16 + fr][kk * 32 + fg * 8];
#pragma unroll
            for (int nt = 0; nt < 2; nt++)
                bb[nt] = *(const bf8_t*)&Bl[wn + nt * 16 + fr][kk * 32 + fg * 8];
#pragma unroll
            for (int mt = 0; mt < 4; mt++)
#pragma unroll
                for (int nt = 0; nt < 2; nt++)
                    acc[mt][nt] = __builtin_amdgcn_mfma_f32_16x16x32_bf16(
                        a[mt], bb[nt], acc[mt][nt], 0, 0, 0);
        }
        __syncthreads();
    }
    // epilogue. C/D: col = lane&15, row = (lane>>4)*4 + reg   [m89/m91]
#pragma unroll
    for (int nt = 0; nt < 2; nt++) {
        int ng = bn + wn + nt * 16 + fr;
        float bvv = bias[ng];
        if (job == 0) {
            int hh = ng & 63;
#pragma unroll
            for (int mt = 0; mt < 4; mt++) {
#pragma unroll
                for (int r = 0; r < 4; r++) {
                    int rg = bm + wm + mt * 16 + fg * 4 + r;
                    int bb2 = rg >> 10, t = rg & 1023;
                    KSb[(((size_t)bb2 * 12 + z) * 1024 + t) * 64 + hh] =
                        f2bf(ftanh(acc[mt][nt][r] + bvv));
                }
            }
        } else {
            unsigned short* out = (job == 1) ? QSbf : WQLbf;
            int Mw = (job == 1) ? 208 : 64;
#pragma unroll
            for (int mt = 0; mt < 4; mt++) {
#pragma unroll
                for (int r = 0; r < 4; r++) {
                    int rg = bm + wm + mt * 16 + fg * 4 + r;
                    if (rg < Mw)
                        out[(size_t)rg * 768 + ng] = f2bf(acc[mt][nt][r] + bvv);
                }
            }
        }
    }
}

// ---- KW[b,c,z,t] = sum_h THbf[b,t,zh] * WQLbf[c][zh]; M=128 N=64 K=64 -----
__global__ __launch_bounds__(256) void kw_mfma_kernel(
    const unsigned short* __restrict__ THbf, const unsigned short* __restrict__ WQLbf,
    float* __restrict__ KW)
{
    __shared__ unsigned short Al[128][72];
    __shared__ unsigned short Bl[64][72];
    const int bid = blockIdx.x, tid = threadIdx.x;
    const int z = bid % 12, bm = (bid / 12) * 128;
    const int lane = tid & 63, w = tid >> 6;
    const int wm = w * 32;
    const int fr = lane & 15, fg = lane >> 4;

#pragma unroll
    for (int i = 0; i < 4; i++) {
        int f = tid + i * 256;
        int r = f >> 3, c8 = (f & 7) << 3;
        *(bf8_t*)&Al[r][c8] = *(const bf8_t*)&THbf[(size_t)(bm + r) * 768 + z * 64 + c8];
    }
#pragma unroll
    for (int i = 0; i < 2; i++) {
        int f = tid + i * 256;
        int r = f >> 3, c8 = (f & 7) << 3;
        *(bf8_t*)&Bl[r][c8] = *(const bf8_t*)&WQLbf[(size_t)r * 768 + z * 64 + c8];
    }
    __syncthreads();

    f32x4 acc[2][4] = {};
#pragma unroll
    for (int kk = 0; kk < 2; kk++) {
        bf8_t a[2], bb[4];
#pragma unroll
        for (int mt = 0; mt < 2; mt++)
            a[mt] = *(const bf8_t*)&Al[wm + mt * 16 + fr][kk * 32 + fg * 8];
#pragma unroll
        for (int nt = 0; nt < 4; nt++)
            bb[nt] = *(const bf8_t*)&Bl[nt * 16 + fr][kk * 32 + fg * 8];
#pragma unroll
        for (int mt = 0; mt < 2; mt++)
#pragma unroll
            for (int nt = 0; nt < 4; nt++)
                acc[mt][nt] = __builtin_amdgcn_mfma_f32_16x16x32_bf16(
                    a[mt], bb[nt], acc[mt][nt], 0, 0, 0);
    }
#pragma unroll
    for (int nt = 0; nt < 4; nt++) {
        int c = nt * 16 + fr;
        if (c < 50) {
#pragma unroll
            for (int mt = 0; mt < 2; mt++) {
#pragma unroll
                for (int r = 0; r < 4; r++) {
                    int rg = bm + wm + mt * 16 + fg * 4 + r;
                    int b = rg >> 10, t = rg & 1023;
                    KW[(((size_t)b * 50 + c) * 12 + z) * 1024 + t] = acc[mt][nt][r];
                }
            }
        }
    }
}

// ---- attn5: MFMA scores + per-lane online softmax -------------------------
// block = (b, z, ts of 128 t); 4 waves; wave w owns cs-tiles nt = w,w+4,w+8[,12].
// A = KS t-rows (m), B = QS cs-rows (n): D col = cs (lane&15), row = t (fg*4+r).
__global__ __launch_bounds__(256) void attn5_kernel(
    const unsigned short* __restrict__ KSb, const unsigned short* __restrict__ QSbf,
    const float* __restrict__ KW,
    float* __restrict__ pm, float* __restrict__ pd, float* __restrict__ pn)
{
    __shared__ unsigned short Kl[128][72];
    __shared__ unsigned short Ql[208][72];
    const int blk = blockIdx.x;
    const int ts = blk & 7;
    const int z  = (blk >> 3) % 12;
    const int b  = blk / 96;
    const int tid = threadIdx.x;
    const int lane = tid & 63, w = tid >> 6;
    const int fr = lane & 15, fg = lane >> 4;

    const unsigned short* ksb = KSb + ((size_t)((b * 12 + z) * 1024) + ts * 128) * 64;
#pragma unroll
    for (int i = 0; i < 4; i++) {
        int f = tid + i * 256;
        int r = f >> 3, c8 = (f & 7) << 3;
        *(bf8_t*)&Kl[r][c8] = *(const bf8_t*)&ksb[(size_t)r * 64 + c8];
    }
#pragma unroll
    for (int i = 0; i < 7; i++) {
        int f = tid + i * 256;
        if (f < 1664) {
            int r = f >> 3, c8 = (f & 7) << 3;
            *(bf8_t*)&Ql[r][c8] = *(const bf8_t*)&QSbf[(size_t)r * 768 + z * 64 + c8];
        }
    }
    __syncthreads();

    bf8_t af[16];
#pragma unroll
    for (int mt = 0; mt < 8; mt++)
#pragma unroll
        for (int kk = 0; kk < 2; kk++)
            af[mt * 2 + kk] = *(const bf8_t*)&Kl[mt * 16 + fr][kk * 32 + fg * 8];

    for (int nt = w; nt < 13; nt += 4) {
        bf8_t b0 = *(const bf8_t*)&Ql[nt * 16 + fr][fg * 8];
        bf8_t b1 = *(const bf8_t*)&Ql[nt * 16 + fr][32 + fg * 8];
        const int cs = nt * 16 + fr;
        const bool live = (cs < 200);
        const float* kwb = live
            ? &KW[(((size_t)b * 50 + (cs >> 2)) * 12 + z) * 1024 + ts * 128] : nullptr;

        float m = -INFINITY, den = 0.f, num = 0.f;
#pragma unroll
        for (int mt = 0; mt < 8; mt++) {
            f32x4 acc = {};
            acc = __builtin_amdgcn_mfma_f32_16x16x32_bf16(af[mt * 2 + 0], b0, acc, 0, 0, 0);
            acc = __builtin_amdgcn_mfma_f32_16x16x32_bf16(af[mt * 2 + 1], b1, acc, 0, 0, 0);
            float4 kw = make_float4(0.f, 0.f, 0.f, 0.f);
            if (live) kw = *(const float4*)&kwb[mt * 16 + fg * 4];
            float pmax = fmaxf(fmaxf(acc[0], acc[1]), fmaxf(acc[2], acc[3]));
            float mn = fmaxf(m, pmax);
            float sc = __expf(m - mn);           // first tile: exp(-inf)=0
            float p0 = __expf(acc[0] - mn);
            float p1 = __expf(acc[1] - mn);
            float p2 = __expf(acc[2] - mn);
            float p3 = __expf(acc[3] - mn);
            den = den * sc + (p0 + p1 + p2 + p3);
            num = num * sc + (p0 * kw.x + p1 * kw.y + p2 * kw.z + p3 * kw.w);
            m = mn;
        }
        // merge across fg groups (lanes fr, fr+16, fr+32, fr+48)
#pragma unroll
        for (int off = 16; off <= 32; off <<= 1) {
            float m2 = __shfl_xor(m, off);
            float d2 = __shfl_xor(den, off);
            float n2 = __shfl_xor(num, off);
            float mn = fmaxf(m, m2);
            float e1 = __expf(m - mn), e2 = __expf(m2 - mn);
            den = den * e1 + d2 * e2;
            num = num * e1 + n2 * e2;
            m = mn;
        }
        if (fg == 0 && live) {
            size_t R = ((size_t)b * 200 + cs) * 12 + z;
            pm[R * 8 + ts] = m;
            pd[R * 8 + ts] = den;
            pn[R * 8 + ts] = num;
        }
    }
}

// ---- merge 8 t-partials per (b,cs,z) row, accumulate into out -------------
__global__ __launch_bounds__(256) void attn_reduce_kernel(
    const float* __restrict__ pm, const float* __restrict__ pd,
    const float* __restrict__ pn, float* __restrict__ out)
{
    int R = blockIdx.x * 256 + threadIdx.x;
    if (R >= 9600) return;
    float M = -INFINITY;
#pragma unroll
    for (int i = 0; i < 8; i++) M = fmaxf(M, pm[R * 8 + i]);
    float D = 0.f, Nn = 0.f;
#pragma unroll
    for (int i = 0; i < 8; i++) {
        float e = __expf(pm[R * 8 + i] - M);
        D  += pd[R * 8 + i] * e;
        Nn += pn[R * 8 + i] * e;
    }
    int zz = R % 12;  (void)zz;
    int q  = R / 12;
    int cs = q % 200, b = q / 200;
    atomicAdd(&out[b * 50 + (cs >> 2)], 0.25f * Nn / D);
}

extern "C" void kernel_launch(void* const* d_in, const int* in_sizes, int n_in,
                              void* d_out, int out_size, void* d_ws, size_t ws_size,
                              hipStream_t stream) {
    const float* Q    = (const float*)d_in[0];
    const float* H    = (const float*)d_in[1];
    const float* ql   = (const float*)d_in[2];
    const float* WQ_w = (const float*)d_in[3];
    const float* WQ_b = (const float*)d_in[4];
    const float* WK_w = (const float*)d_in[5];
    const float* WK_b = (const float*)d_in[6];
    const float* WV_w = (const float*)d_in[7];
    const float* WV_b = (const float*)d_in[8];
    float* out = (float*)d_out;

    float* ws = (float*)d_ws;
    // f32-slot layout (KW aliases [Hbf|WTk|WTq|WTv], dead after gemm_all):
    unsigned short* KSb  = (unsigned short*)ws;              // 1,572,864 f32
    float* aliasA        = ws + 1572864;
    unsigned short* Hbf  = (unsigned short*)aliasA;          // 1,572,864 f32
    unsigned short* WTk  = (unsigned short*)(aliasA + 1572864);  // 294,912
    unsigned short* WTq  = (unsigned short*)(aliasA + 1867776);  // 294,912
    unsigned short* WTv  = (unsigned short*)(aliasA + 2162688);  // 294,912
    float* KW            = aliasA;                           // 2,457,600 (alias)
    unsigned short* THbf = (unsigned short*)(ws + 4030464);  // 1,572,864
    unsigned short* Qbf  = (unsigned short*)(ws + 5603328);  //    76,800
    unsigned short* qlbf = (unsigned short*)(ws + 5680128);  //    19,200
    unsigned short* QSbf = (unsigned short*)(ws + 5699328);  //    79,872
    unsigned short* WQLbf= (unsigned short*)(ws + 5779200);  //    24,576
    float* pm            = ws + 5803776;                     //    76,800
    float* pd            = ws + 5880576;                     //    76,800
    float* pn            = ws + 5957376;                     //    76,800
    (void)in_sizes; (void)n_in; (void)out_size; (void)ws_size;

    hipMemsetAsync(d_out, 0, 200 * sizeof(float), stream);

    prep_kernel<<<2062, 256, 0, stream>>>(H, WK_w, WQ_w, WV_w, Q, ql,
                                          Hbf, THbf, WTk, WTq, WTv, Qbf, qlbf);
    gemm_all_kernel<<<420, 256, 0, stream>>>(Hbf, Qbf, qlbf, WTk, WTq, WTv,
                                             WK_b, WQ_b, WV_b, KSb, QSbf, WQLbf);
    kw_mfma_kernel<<<384, 256, 0, stream>>>(THbf, WQLbf, KW);
    attn5_kernel<<<384, 256, 0, stream>>>(KSb, QSbf, KW, pm, pd, pn);
    attn_reduce_kernel<<<38, 256, 0, stream>>>(pm, pd, pn, out);
}

// Round 7
// 147.730 us; speedup vs baseline: 2.8969x; 1.0338x over previous
//
#include <hip/hip_runtime.h>
#include <hip/hip_bf16.h>
#include <cmath>

// ---------------------------------------------------------------------------
// MultiSynonymsAttention: c=50 s=4 d=768 b=4 t=1024 z=12 h=64
// 4 dispatches:
//  prep    : Hbf=bf16(H), THbf=bf16(ftanh(H)), WTk/q/v=bf16(W^T), Qbf, qlbf
//  gemm_all: job0 KSb = bf16(ftanh(Hbf@WTk^T + bk))   [b][z][t][64]
//            job1 QSbf = bf16(Qbf@WTq^T + bq)         [208][768]
//            job2 WQLbf = bf16(qlbf@WTv^T + bv)       [64][768]
//  attn6   : per (b,z,ts): kw tile (MFMA, LDS) + scores (MFMA) + exp-sums
//            (no max subtraction: |score| <~ 15, f32-safe) -> pd/pn partials
//  reduce  : one block; out[b,c] = 0.25 * sum_{z,s} (sum_ts pn)/(sum_ts pd)
// ---------------------------------------------------------------------------

typedef __attribute__((ext_vector_type(8))) short bf8_t;
typedef __attribute__((ext_vector_type(4))) float f32x4;

__device__ inline unsigned short f2bf(float x) {            // RNE f32->bf16
    unsigned u = __float_as_uint(x);
    return (unsigned short)((u + 0x7fffu + ((u >> 16) & 1u)) >> 16);
}
__device__ inline float ftanh(float x) {                    // 1 - 2/(e^2x+1)
    float t = __expf(2.f * x);                              // +inf -> 1
    return 1.f - 2.f * __builtin_amdgcn_rcpf(t + 1.f);      // -inf -> -1
}

// ---- prep: all input conversions in one launch ----------------------------
__global__ __launch_bounds__(256) void prep_kernel(
    const float* __restrict__ H, const float* __restrict__ WK,
    const float* __restrict__ WQ, const float* __restrict__ WV,
    const float* __restrict__ Q, const float* __restrict__ ql,
    unsigned short* __restrict__ Hbf, unsigned short* __restrict__ THbf,
    unsigned short* __restrict__ WTk, unsigned short* __restrict__ WTq,
    unsigned short* __restrict__ WTv,
    unsigned short* __restrict__ Qbf, unsigned short* __restrict__ qlbf)
{
    __shared__ unsigned short tile[64][72];
    const int bid = blockIdx.x, tid = threadIdx.x;
    if (bid < 1536) {
        int i = (bid * 256 + tid) * 8;
        float4 v0 = *(const float4*)&H[i];
        float4 v1 = *(const float4*)&H[i + 4];
        unsigned short h8[8] = {f2bf(v0.x), f2bf(v0.y), f2bf(v0.z), f2bf(v0.w),
                                f2bf(v1.x), f2bf(v1.y), f2bf(v1.z), f2bf(v1.w)};
        *(bf8_t*)&Hbf[i] = *(const bf8_t*)h8;
        unsigned short t8[8] = {f2bf(ftanh(v0.x)), f2bf(ftanh(v0.y)),
                                f2bf(ftanh(v0.z)), f2bf(ftanh(v0.w)),
                                f2bf(ftanh(v1.x)), f2bf(ftanh(v1.y)),
                                f2bf(ftanh(v1.z)), f2bf(ftanh(v1.w))};
        *(bf8_t*)&THbf[i] = *(const bf8_t*)t8;
    } else if (bid < 1968) {
        int j = bid - 1536;
        int wsel = j / 144, l = j % 144;
        const float* W = (wsel == 0) ? WK : (wsel == 1) ? WQ : WV;
        unsigned short* WT = (wsel == 0) ? WTk : (wsel == 1) ? WTq : WTv;
        const int bn = (l % 12) * 64, bk = (l / 12) * 64;
        const int k = tid >> 4, n4 = (tid & 15) << 2;
#pragma unroll
        for (int i = 0; i < 4; i++) {
            int kk = k + i * 16;
            float4 v = *(const float4*)&W[(size_t)(bk + kk) * 768 + bn + n4];
            tile[n4 + 0][kk] = f2bf(v.x);
            tile[n4 + 1][kk] = f2bf(v.y);
            tile[n4 + 2][kk] = f2bf(v.z);
            tile[n4 + 3][kk] = f2bf(v.w);
        }
        __syncthreads();
#pragma unroll
        for (int i = 0; i < 2; i++) {
            int idx = tid + i * 256;
            int n = idx >> 3, k8 = (idx & 7) << 3;
            *(bf8_t*)&WT[(size_t)(bn + n) * 768 + bk + k8] = *(const bf8_t*)&tile[n][k8];
        }
    } else if (bid < 2043) {
        int i = ((bid - 1968) * 256 + tid) * 8;
        float4 v0 = *(const float4*)&Q[i];
        float4 v1 = *(const float4*)&Q[i + 4];
        unsigned short h8[8] = {f2bf(v0.x), f2bf(v0.y), f2bf(v0.z), f2bf(v0.w),
                                f2bf(v1.x), f2bf(v1.y), f2bf(v1.z), f2bf(v1.w)};
        *(bf8_t*)&Qbf[i] = *(const bf8_t*)h8;
    } else {
        int i = ((bid - 2043) * 256 + tid) * 8;
        if (i < 38400) {
            float4 v0 = *(const float4*)&ql[i];
            float4 v1 = *(const float4*)&ql[i + 4];
            unsigned short h8[8] = {f2bf(v0.x), f2bf(v0.y), f2bf(v0.z), f2bf(v0.w),
                                    f2bf(v1.x), f2bf(v1.y), f2bf(v1.z), f2bf(v1.w)};
            *(bf8_t*)&qlbf[i] = *(const bf8_t*)h8;
        }
    }
}

// ---- unified bf16 MFMA GEMM: 128x64 tile, K=768, 3 job types --------------
__global__ __launch_bounds__(256) void gemm_all_kernel(
    const unsigned short* __restrict__ Hbf, const unsigned short* __restrict__ Qbf,
    const unsigned short* __restrict__ qlbf,
    const unsigned short* __restrict__ WTk, const unsigned short* __restrict__ WTq,
    const unsigned short* __restrict__ WTv,
    const float* __restrict__ bk, const float* __restrict__ bq,
    const float* __restrict__ bv,
    unsigned short* __restrict__ KSb, unsigned short* __restrict__ QSbf,
    unsigned short* __restrict__ WQLbf)
{
    __shared__ unsigned short Al[128][72];
    __shared__ unsigned short Bl[64][72];
    const int bid = blockIdx.x, tid = threadIdx.x;
    int job, bm, bn, Mr, z = 0;
    const unsigned short *A, *B;
    const float* bias;
    if (bid < 384) {
        job = 0; z = bid % 12; bm = (bid / 12) * 128; bn = z * 64;
        A = Hbf; B = WTk; bias = bk; Mr = 4096;
    } else if (bid < 408) {
        int l = bid - 384;
        job = 1; bm = (l / 12) * 128; bn = (l % 12) * 64;
        A = Qbf; B = WTq; bias = bq; Mr = 200;
    } else {
        job = 2; bm = 0; bn = (bid - 408) * 64;
        A = qlbf; B = WTv; bias = bv; Mr = 50;
    }
    const int lane = tid & 63, w = tid >> 6;
    const int wm = (w & 1) * 64, wn = (w >> 1) * 32;
    const int fr = lane & 15, fg = lane >> 4;

    f32x4 acc[4][2] = {};

    for (int k0 = 0; k0 < 768; k0 += 64) {
#pragma unroll
        for (int i = 0; i < 4; i++) {
            int f = tid + i * 256;
            int r = f >> 3, c8 = (f & 7) << 3;
            bf8_t v = {};
            if (bm + r < Mr)
                v = *(const bf8_t*)&A[(size_t)(bm + r) * 768 + k0 + c8];
            *(bf8_t*)&Al[r][c8] = v;
        }
#pragma unroll
        for (int i = 0; i < 2; i++) {
            int f = tid + i * 256;
            int r = f >> 3, c8 = (f & 7) << 3;
            *(bf8_t*)&Bl[r][c8] = *(const bf8_t*)&B[(size_t)(bn + r) * 768 + k0 + c8];
        }
        __syncthreads();
#pragma unroll
        for (int kk = 0; kk < 2; kk++) {
            bf8_t a[4], bb[2];
#pragma unroll
            for (int mt = 0; mt < 4; mt++)
                a[mt] = *(const bf8_t*)&Al[wm + mt * 16 + fr][kk * 32 + fg * 8];
#pragma unroll
            for (int nt = 0; nt < 2; nt++)
                bb[nt] = *(const bf8_t*)&Bl[wn + nt * 16 + fr][kk * 32 + fg * 8];
#pragma unroll
            for (int mt = 0; mt < 4; mt++)
#pragma unroll
                for (int nt = 0; nt < 2; nt++)
                    acc[mt][nt] = __builtin_amdgcn_mfma_f32_16x16x32_bf16(
                        a[mt], bb[nt], acc[mt][nt], 0, 0, 0);
        }
        __syncthreads();
    }
    // C/D: col = lane&15, row = (lane>>4)*4 + reg   [m89/m91]
#pragma unroll
    for (int nt = 0; nt < 2; nt++) {
        int ng = bn + wn + nt * 16 + fr;
        float bvv = bias[ng];
        if (job == 0) {
            int hh = ng & 63;
#pragma unroll
            for (int mt = 0; mt < 4; mt++) {
#pragma unroll
                for (int r = 0; r < 4; r++) {
                    int rg = bm + wm + mt * 16 + fg * 4 + r;
                    int bb2 = rg >> 10, t = rg & 1023;
                    KSb[(((size_t)bb2 * 12 + z) * 1024 + t) * 64 + hh] =
                        f2bf(ftanh(acc[mt][nt][r] + bvv));
                }
            }
        } else {
            unsigned short* outp = (job == 1) ? QSbf : WQLbf;
            int Mw = (job == 1) ? 208 : 64;
#pragma unroll
            for (int mt = 0; mt < 4; mt++) {
#pragma unroll
                for (int r = 0; r < 4; r++) {
                    int rg = bm + wm + mt * 16 + fg * 4 + r;
                    if (rg < Mw)
                        outp[(size_t)rg * 768 + ng] = f2bf(acc[mt][nt][r] + bvv);
                }
            }
        }
    }
}

// ---- attn6: fused kw-tile + MFMA scores + exp-sums (no max needed) --------
// block = (b, z, ts of 128 t); 4 waves.
// phase1: kwl[t][c] = THl @ Wl^T (MFMA, wave w does t-rows w*32..+32)
// phase3: scores D[t][cs] = Kl @ QS^T; den=sum e^s, num=sum e^s*kwl
__global__ __launch_bounds__(256) void attn6_kernel(
    const unsigned short* __restrict__ KSb, const unsigned short* __restrict__ QSbf,
    const unsigned short* __restrict__ THbf, const unsigned short* __restrict__ WQLbf,
    float* __restrict__ pd, float* __restrict__ pn)
{
    __shared__ unsigned short KTl[128][72];   // phase1: TH tile; phase3: K tile
    __shared__ unsigned short Wl[64][72];
    __shared__ float kwl[128][50];
    const int blk = blockIdx.x;
    const int ts = blk & 7;
    const int z  = (blk >> 3) % 12;
    const int b  = blk / 96;
    const int tid = threadIdx.x;
    const int lane = tid & 63, w = tid >> 6;
    const int fr = lane & 15, fg = lane >> 4;

    // phase 0: stage TH (t-chunk) + WQL slice
    const unsigned short* thb = THbf + ((size_t)(b * 1024 + ts * 128)) * 768 + z * 64;
#pragma unroll
    for (int i = 0; i < 4; i++) {
        int f = tid + i * 256;
        int r = f >> 3, c8 = (f & 7) << 3;
        *(bf8_t*)&KTl[r][c8] = *(const bf8_t*)&thb[(size_t)r * 768 + c8];
    }
#pragma unroll
    for (int i = 0; i < 2; i++) {
        int f = tid + i * 256;
        int r = f >> 3, c8 = (f & 7) << 3;
        *(bf8_t*)&Wl[r][c8] = *(const bf8_t*)&WQLbf[(size_t)r * 768 + z * 64 + c8];
    }
    __syncthreads();

    // phase 1: kw tile (M=32/wave x N=64, K=64)
    {
        const int wm = w * 32;
        f32x4 acc[2][4] = {};
#pragma unroll
        for (int kk = 0; kk < 2; kk++) {
            bf8_t a[2], bb[4];
#pragma unroll
            for (int mt = 0; mt < 2; mt++)
                a[mt] = *(const bf8_t*)&KTl[wm + mt * 16 + fr][kk * 32 + fg * 8];
#pragma unroll
            for (int nt = 0; nt < 4; nt++)
                bb[nt] = *(const bf8_t*)&Wl[nt * 16 + fr][kk * 32 + fg * 8];
#pragma unroll
            for (int mt = 0; mt < 2; mt++)
#pragma unroll
                for (int nt = 0; nt < 4; nt++)
                    acc[mt][nt] = __builtin_amdgcn_mfma_f32_16x16x32_bf16(
                        a[mt], bb[nt], acc[mt][nt], 0, 0, 0);
        }
#pragma unroll
        for (int nt = 0; nt < 4; nt++) {
            int c = nt * 16 + fr;
            if (c < 50) {
#pragma unroll
                for (int mt = 0; mt < 2; mt++)
#pragma unroll
                    for (int r = 0; r < 4; r++)
                        kwl[wm + mt * 16 + fg * 4 + r][c] = acc[mt][nt][r];
            }
        }
    }
    __syncthreads();

    // phase 2: stage K tile over TH tile
    const unsigned short* ksb = KSb + ((size_t)((b * 12 + z) * 1024) + ts * 128) * 64;
#pragma unroll
    for (int i = 0; i < 4; i++) {
        int f = tid + i * 256;
        int r = f >> 3, c8 = (f & 7) << 3;
        *(bf8_t*)&KTl[r][c8] = *(const bf8_t*)&ksb[(size_t)r * 64 + c8];
    }
    __syncthreads();

    // phase 3: scores + exp-sums. wave w owns cs-tiles nt = w, w+4, w+8[, 12].
    bf8_t af[16];
#pragma unroll
    for (int mt = 0; mt < 8; mt++)
#pragma unroll
        for (int kk = 0; kk < 2; kk++)
            af[mt * 2 + kk] = *(const bf8_t*)&KTl[mt * 16 + fr][kk * 32 + fg * 8];

    for (int nt = w; nt < 13; nt += 4) {
        const int cs = nt * 16 + fr;
        const bool live = (cs < 200);
        const int kc = live ? (cs >> 2) : 0;
        bf8_t b0 = *(const bf8_t*)&QSbf[(size_t)(nt * 16 + fr) * 768 + z * 64 + fg * 8];
        bf8_t b1 = *(const bf8_t*)&QSbf[(size_t)(nt * 16 + fr) * 768 + z * 64 + 32 + fg * 8];

        float den = 0.f, num = 0.f;
#pragma unroll
        for (int mt = 0; mt < 8; mt++) {
            f32x4 acc = {};
            acc = __builtin_amdgcn_mfma_f32_16x16x32_bf16(af[mt * 2 + 0], b0, acc, 0, 0, 0);
            acc = __builtin_amdgcn_mfma_f32_16x16x32_bf16(af[mt * 2 + 1], b1, acc, 0, 0, 0);
#pragma unroll
            for (int j = 0; j < 4; j++) {
                float p = __expf(acc[j]);               // |score| <~ 15: safe
                den += p;
                num += p * kwl[mt * 16 + fg * 4 + j][kc];
            }
        }
        den += __shfl_xor(den, 16); num += __shfl_xor(num, 16);
        den += __shfl_xor(den, 32); num += __shfl_xor(num, 32);
        if (fg == 0 && live) {
            size_t R = ((size_t)b * 200 + cs) * 12 + z;
            pd[R * 8 + ts] = den;
            pn[R * 8 + ts] = num;
        }
    }
}

// ---- reduce: one block; thread i owns out[b,c]; no atomics, no init -------
__global__ __launch_bounds__(256) void reduce_kernel(
    const float* __restrict__ pd, const float* __restrict__ pn,
    float* __restrict__ out)
{
    int i = threadIdx.x;
    if (i >= 200) return;
    int b = i / 50, c = i % 50;
    float acc = 0.f;
    for (int s = 0; s < 4; s++) {
#pragma unroll
        for (int z = 0; z < 12; z++) {
            size_t R = ((size_t)b * 200 + (c * 4 + s)) * 12 + z;
            float D = 0.f, N = 0.f;
#pragma unroll
            for (int t = 0; t < 8; t++) {
                D += pd[R * 8 + t];
                N += pn[R * 8 + t];
            }
            acc += N / D;
        }
    }
    out[i] = 0.25f * acc;
}

extern "C" void kernel_launch(void* const* d_in, const int* in_sizes, int n_in,
                              void* d_out, int out_size, void* d_ws, size_t ws_size,
                              hipStream_t stream) {
    const float* Q    = (const float*)d_in[0];
    const float* H    = (const float*)d_in[1];
    const float* ql   = (const float*)d_in[2];
    const float* WQ_w = (const float*)d_in[3];
    const float* WQ_b = (const float*)d_in[4];
    const float* WK_w = (const float*)d_in[5];
    const float* WK_b = (const float*)d_in[6];
    const float* WV_w = (const float*)d_in[7];
    const float* WV_b = (const float*)d_in[8];
    float* out = (float*)d_out;

    float* ws = (float*)d_ws;                               // f32-slot offsets
    unsigned short* KSb   = (unsigned short*)ws;             // 1,572,864
    unsigned short* Hbf   = (unsigned short*)(ws + 1572864); // 1,572,864
    unsigned short* THbf  = (unsigned short*)(ws + 3145728); // 1,572,864
    unsigned short* WTk   = (unsigned short*)(ws + 4718592); //   294,912
    unsigned short* WTq   = (unsigned short*)(ws + 5013504); //   294,912
    unsigned short* WTv   = (unsigned short*)(ws + 5308416); //   294,912
    unsigned short* Qbf   = (unsigned short*)(ws + 5603328); //    76,800
    unsigned short* qlbf  = (unsigned short*)(ws + 5680128); //    19,200
    unsigned short* QSbf  = (unsigned short*)(ws + 5699328); //    79,872
    unsigned short* WQLbf = (unsigned short*)(ws + 5779200); //    24,576
    float* pd             = ws + 5803776;                    //    76,800
    float* pn             = ws + 5880576;                    //    76,800
    (void)in_sizes; (void)n_in; (void)out_size; (void)ws_size;

    prep_kernel<<<2062, 256, 0, stream>>>(H, WK_w, WQ_w, WV_w, Q, ql,
                                          Hbf, THbf, WTk, WTq, WTv, Qbf, qlbf);
    gemm_all_kernel<<<420, 256, 0, stream>>>(Hbf, Qbf, qlbf, WTk, WTq, WTv,
                                             WK_b, WQ_b, WV_b, KSb, QSbf, WQLbf);
    attn6_kernel<<<384, 256, 0, stream>>>(KSb, QSbf, THbf, WQLbf, pd, pn);
    reduce_kernel<<<1, 256, 0, stream>>>(pd, pn, out);
}

// Round 8
// 123.192 us; speedup vs baseline: 3.4740x; 1.1992x over previous
//
#include <hip/hip_runtime.h>
#include <hip/hip_bf16.h>
#include <cmath>

// ---------------------------------------------------------------------------
// MultiSynonymsAttention: c=50 s=4 d=768 b=4 t=1024 z=12 h=64
// 4 dispatches:
//  prep    : Hbf=bf16(H), WTk/q/v=bf16(W^T), Qbf, qlbf
//  gemm_all: job0 KSb = bf16(ftanh(Hbf@WTk^T + bk))   [b][z][t][64]
//            (job0 bids XCD-swizzled so same-bm z-variants share an L2)
//            job1 QSbf = bf16(Qbf@WTq^T + bq)         [208][768]
//            job2 WQLbf = bf16(qlbf@WTv^T + bv)       [64][768]
//  attn7   : per (b,z,ts): tanh(H) tile staged in-kernel -> kw tile (MFMA,
//            LDS) + scores (MFMA) + exp-sums (no max: |score| <~ 15) -> pd/pn
//  reduce  : block per (b,c), 64 lanes; ratio per (z,s), wave-reduce
// ---------------------------------------------------------------------------

typedef __attribute__((ext_vector_type(8))) short bf8_t;
typedef __attribute__((ext_vector_type(4))) float f32x4;

__device__ inline unsigned short f2bf(float x) {            // RNE f32->bf16
    unsigned u = __float_as_uint(x);
    return (unsigned short)((u + 0x7fffu + ((u >> 16) & 1u)) >> 16);
}
__device__ inline float ftanh(float x) {                    // 1 - 2/(e^2x+1)
    float t = __expf(2.f * x);                              // +inf -> 1
    return 1.f - 2.f * __builtin_amdgcn_rcpf(t + 1.f);      // -inf -> -1
}

// ---- prep: all input conversions in one launch ----------------------------
// [0,1536): H -> Hbf ; [1536,1968): 3x W^T -> bf16 ; [1968,2043): Q ; rest ql
__global__ __launch_bounds__(256) void prep_kernel(
    const float* __restrict__ H, const float* __restrict__ WK,
    const float* __restrict__ WQ, const float* __restrict__ WV,
    const float* __restrict__ Q, const float* __restrict__ ql,
    unsigned short* __restrict__ Hbf,
    unsigned short* __restrict__ WTk, unsigned short* __restrict__ WTq,
    unsigned short* __restrict__ WTv,
    unsigned short* __restrict__ Qbf, unsigned short* __restrict__ qlbf)
{
    __shared__ unsigned short tile[64][72];
    const int bid = blockIdx.x, tid = threadIdx.x;
    if (bid < 1536) {
        int i = (bid * 256 + tid) * 8;
        float4 v0 = *(const float4*)&H[i];
        float4 v1 = *(const float4*)&H[i + 4];
        unsigned short h8[8] = {f2bf(v0.x), f2bf(v0.y), f2bf(v0.z), f2bf(v0.w),
                                f2bf(v1.x), f2bf(v1.y), f2bf(v1.z), f2bf(v1.w)};
        *(bf8_t*)&Hbf[i] = *(const bf8_t*)h8;
    } else if (bid < 1968) {
        int j = bid - 1536;
        int wsel = j / 144, l = j % 144;
        const float* W = (wsel == 0) ? WK : (wsel == 1) ? WQ : WV;
        unsigned short* WT = (wsel == 0) ? WTk : (wsel == 1) ? WTq : WTv;
        const int bn = (l % 12) * 64, bk = (l / 12) * 64;
        const int k = tid >> 4, n4 = (tid & 15) << 2;
#pragma unroll
        for (int i = 0; i < 4; i++) {
            int kk = k + i * 16;
            float4 v = *(const float4*)&W[(size_t)(bk + kk) * 768 + bn + n4];
            tile[n4 + 0][kk] = f2bf(v.x);
            tile[n4 + 1][kk] = f2bf(v.y);
            tile[n4 + 2][kk] = f2bf(v.z);
            tile[n4 + 3][kk] = f2bf(v.w);
        }
        __syncthreads();
#pragma unroll
        for (int i = 0; i < 2; i++) {
            int idx = tid + i * 256;
            int n = idx >> 3, k8 = (idx & 7) << 3;
            *(bf8_t*)&WT[(size_t)(bn + n) * 768 + bk + k8] = *(const bf8_t*)&tile[n][k8];
        }
    } else if (bid < 2043) {
        int i = ((bid - 1968) * 256 + tid) * 8;
        float4 v0 = *(const float4*)&Q[i];
        float4 v1 = *(const float4*)&Q[i + 4];
        unsigned short h8[8] = {f2bf(v0.x), f2bf(v0.y), f2bf(v0.z), f2bf(v0.w),
                                f2bf(v1.x), f2bf(v1.y), f2bf(v1.z), f2bf(v1.w)};
        *(bf8_t*)&Qbf[i] = *(const bf8_t*)h8;
    } else {
        int i = ((bid - 2043) * 256 + tid) * 8;
        if (i < 38400) {
            float4 v0 = *(const float4*)&ql[i];
            float4 v1 = *(const float4*)&ql[i + 4];
            unsigned short h8[8] = {f2bf(v0.x), f2bf(v0.y), f2bf(v0.z), f2bf(v0.w),
                                    f2bf(v1.x), f2bf(v1.y), f2bf(v1.z), f2bf(v1.w)};
            *(bf8_t*)&qlbf[i] = *(const bf8_t*)h8;
        }
    }
}

// ---- unified bf16 MFMA GEMM: 128x64 tile, K=768, 3 job types --------------
__global__ __launch_bounds__(256) void gemm_all_kernel(
    const unsigned short* __restrict__ Hbf, const unsigned short* __restrict__ Qbf,
    const unsigned short* __restrict__ qlbf,
    const unsigned short* __restrict__ WTk, const unsigned short* __restrict__ WTq,
    const unsigned short* __restrict__ WTv,
    const float* __restrict__ bk, const float* __restrict__ bq,
    const float* __restrict__ bv,
    unsigned short* __restrict__ KSb, unsigned short* __restrict__ QSbf,
    unsigned short* __restrict__ WQLbf)
{
    __shared__ unsigned short Al[128][72];
    __shared__ unsigned short Bl[64][72];
    int bid = blockIdx.x;
    const int tid = threadIdx.x;
    // XCD-swizzle job0 (384 = 8*48, bijective): blocks sharing one Hbf tile
    // (12 consecutive logical z-variants) land on the same XCD's L2.
    if (bid < 384) bid = (bid & 7) * 48 + (bid >> 3);
    int job, bm, bn, Mr, z = 0;
    const unsigned short *A, *B;
    const float* bias;
    if (bid < 384) {
        job = 0; z = bid % 12; bm = (bid / 12) * 128; bn = z * 64;
        A = Hbf; B = WTk; bias = bk; Mr = 4096;
    } else if (bid < 408) {
        int l = bid - 384;
        job = 1; bm = (l / 12) * 128; bn = (l % 12) * 64;
        A = Qbf; B = WTq; bias = bq; Mr = 200;
    } else {
        job = 2; bm = 0; bn = (bid - 408) * 64;
        A = qlbf; B = WTv; bias = bv; Mr = 50;
    }
    const int lane = tid & 63, w = tid >> 6;
    const int wm = (w & 1) * 64, wn = (w >> 1) * 32;
    const int fr = lane & 15, fg = lane >> 4;

    f32x4 acc[4][2] = {};

    for (int k0 = 0; k0 < 768; k0 += 64) {
#pragma unroll
        for (int i = 0; i < 4; i++) {
            int f = tid + i * 256;
            int r = f >> 3, c8 = (f & 7) << 3;
            bf8_t v = {};
            if (bm + r < Mr)
                v = *(const bf8_t*)&A[(size_t)(bm + r) * 768 + k0 + c8];
            *(bf8_t*)&Al[r][c8] = v;
        }
#pragma unroll
        for (int i = 0; i < 2; i++) {
            int f = tid + i * 256;
            int r = f >> 3, c8 = (f & 7) << 3;
            *(bf8_t*)&Bl[r][c8] = *(const bf8_t*)&B[(size_t)(bn + r) * 768 + k0 + c8];
        }
        __syncthreads();
#pragma unroll
        for (int kk = 0; kk < 2; kk++) {
            bf8_t a[4], bb[2];
#pragma unroll
            for (int mt = 0; mt < 4; mt++)
                a[mt] = *(const bf8_t*)&Al[wm + mt * 16 + fr][kk * 32 + fg * 8];
#pragma unroll
            for (int nt = 0; nt < 2; nt++)
                bb[nt] = *(const bf8_t*)&Bl[wn + nt * 16 + fr][kk * 32 + fg * 8];
#pragma unroll
            for (int mt = 0; mt < 4; mt++)
#pragma unroll
                for (int nt = 0; nt < 2; nt++)
                    acc[mt][nt] = __builtin_amdgcn_mfma_f32_16x16x32_bf16(
                        a[mt], bb[nt], acc[mt][nt], 0, 0, 0);
        }
        __syncthreads();
    }
    // C/D: col = lane&15, row = (lane>>4)*4 + reg   [m89/m91]
#pragma unroll
    for (int nt = 0; nt < 2; nt++) {
        int ng = bn + wn + nt * 16 + fr;
        float bvv = bias[ng];
        if (job == 0) {
            int hh = ng & 63;
#pragma unroll
            for (int mt = 0; mt < 4; mt++) {
#pragma unroll
                for (int r = 0; r < 4; r++) {
                    int rg = bm + wm + mt * 16 + fg * 4 + r;
                    int bb2 = rg >> 10, t = rg & 1023;
                    KSb[(((size_t)bb2 * 12 + z) * 1024 + t) * 64 + hh] =
                        f2bf(ftanh(acc[mt][nt][r] + bvv));
                }
            }
        } else {
            unsigned short* outp = (job == 1) ? QSbf : WQLbf;
            int Mw = (job == 1) ? 208 : 64;
#pragma unroll
            for (int mt = 0; mt < 4; mt++) {
#pragma unroll
                for (int r = 0; r < 4; r++) {
                    int rg = bm + wm + mt * 16 + fg * 4 + r;
                    if (rg < Mw)
                        outp[(size_t)rg * 768 + ng] = f2bf(acc[mt][nt][r] + bvv);
                }
            }
        }
    }
}

// ---- attn7: in-kernel tanh(H) + kw tile + MFMA scores + exp-sums ----------
// block = (b, z, ts of 128 t); 4 waves.
__global__ __launch_bounds__(256) void attn7_kernel(
    const unsigned short* __restrict__ KSb, const unsigned short* __restrict__ QSbf,
    const float* __restrict__ H, const unsigned short* __restrict__ WQLbf,
    float* __restrict__ pd, float* __restrict__ pn)
{
    __shared__ unsigned short KTl[128][72];   // phase1: tanh(H); phase3: K tile
    __shared__ unsigned short Wl[64][72];
    __shared__ float kwl[128][50];
    const int blk = blockIdx.x;
    const int ts = blk & 7;
    const int z  = (blk >> 3) % 12;
    const int b  = blk / 96;
    const int tid = threadIdx.x;
    const int lane = tid & 63, w = tid >> 6;
    const int fr = lane & 15, fg = lane >> 4;

    // phase 0: stage tanh(H) tile (f32 load, ftanh, bf16 pack) + WQL slice
    const float* hb = H + ((size_t)(b * 1024 + ts * 128)) * 768 + z * 64;
#pragma unroll
    for (int i = 0; i < 4; i++) {
        int f = tid + i * 256;
        int r = f >> 3, c8 = (f & 7) << 3;
        float4 v0 = *(const float4*)&hb[(size_t)r * 768 + c8];
        float4 v1 = *(const float4*)&hb[(size_t)r * 768 + c8 + 4];
        unsigned short t8[8] = {f2bf(ftanh(v0.x)), f2bf(ftanh(v0.y)),
                                f2bf(ftanh(v0.z)), f2bf(ftanh(v0.w)),
                                f2bf(ftanh(v1.x)), f2bf(ftanh(v1.y)),
                                f2bf(ftanh(v1.z)), f2bf(ftanh(v1.w))};
        *(bf8_t*)&KTl[r][c8] = *(const bf8_t*)t8;
    }
#pragma unroll
    for (int i = 0; i < 2; i++) {
        int f = tid + i * 256;
        int r = f >> 3, c8 = (f & 7) << 3;
        *(bf8_t*)&Wl[r][c8] = *(const bf8_t*)&WQLbf[(size_t)r * 768 + z * 64 + c8];
    }
    __syncthreads();

    // phase 1: kw tile (M=32/wave x N=64, K=64)
    {
        const int wm = w * 32;
        f32x4 acc[2][4] = {};
#pragma unroll
        for (int kk = 0; kk < 2; kk++) {
            bf8_t a[2], bb[4];
#pragma unroll
            for (int mt = 0; mt < 2; mt++)
                a[mt] = *(const bf8_t*)&KTl[wm + mt * 16 + fr][kk * 32 + fg * 8];
#pragma unroll
            for (int nt = 0; nt < 4; nt++)
                bb[nt] = *(const bf8_t*)&Wl[nt * 16 + fr][kk * 32 + fg * 8];
#pragma unroll
            for (int mt = 0; mt < 2; mt++)
#pragma unroll
                for (int nt = 0; nt < 4; nt++)
                    acc[mt][nt] = __builtin_amdgcn_mfma_f32_16x16x32_bf16(
                        a[mt], bb[nt], acc[mt][nt], 0, 0, 0);
        }
#pragma unroll
        for (int nt = 0; nt < 4; nt++) {
            int c = nt * 16 + fr;
            if (c < 50) {
#pragma unroll
                for (int mt = 0; mt < 2; mt++)
#pragma unroll
                    for (int r = 0; r < 4; r++)
                        kwl[wm + mt * 16 + fg * 4 + r][c] = acc[mt][nt][r];
            }
        }
    }
    __syncthreads();

    // phase 2: stage K tile over the tanh(H) tile
    const unsigned short* ksb = KSb + ((size_t)((b * 12 + z) * 1024) + ts * 128) * 64;
#pragma unroll
    for (int i = 0; i < 4; i++) {
        int f = tid + i * 256;
        int r = f >> 3, c8 = (f & 7) << 3;
        *(bf8_t*)&KTl[r][c8] = *(const bf8_t*)&ksb[(size_t)r * 64 + c8];
    }
    __syncthreads();

    // phase 3: scores + exp-sums. wave w owns cs-tiles nt = w, w+4, w+8[, 12].
    bf8_t af[16];
#pragma unroll
    for (int mt = 0; mt < 8; mt++)
#pragma unroll
        for (int kk = 0; kk < 2; kk++)
            af[mt * 2 + kk] = *(const bf8_t*)&KTl[mt * 16 + fr][kk * 32 + fg * 8];

    for (int nt = w; nt < 13; nt += 4) {
        const int cs = nt * 16 + fr;
        const bool live = (cs < 200);
        const int kc = live ? (cs >> 2) : 0;
        bf8_t b0 = *(const bf8_t*)&QSbf[(size_t)(nt * 16 + fr) * 768 + z * 64 + fg * 8];
        bf8_t b1 = *(const bf8_t*)&QSbf[(size_t)(nt * 16 + fr) * 768 + z * 64 + 32 + fg * 8];

        float den = 0.f, num = 0.f;
#pragma unroll
        for (int mt = 0; mt < 8; mt++) {
            f32x4 acc = {};
            acc = __builtin_amdgcn_mfma_f32_16x16x32_bf16(af[mt * 2 + 0], b0, acc, 0, 0, 0);
            acc = __builtin_amdgcn_mfma_f32_16x16x32_bf16(af[mt * 2 + 1], b1, acc, 0, 0, 0);
#pragma unroll
            for (int j = 0; j < 4; j++) {
                float p = __expf(acc[j]);               // |score| <~ 15: safe
                den += p;
                num += p * kwl[mt * 16 + fg * 4 + j][kc];
            }
        }
        den += __shfl_xor(den, 16); num += __shfl_xor(num, 16);
        den += __shfl_xor(den, 32); num += __shfl_xor(num, 32);
        if (fg == 0 && live) {
            size_t R = ((size_t)b * 200 + cs) * 12 + z;
            pd[R * 8 + ts] = den;
            pn[R * 8 + ts] = num;
        }
    }
}

// ---- reduce: block per (b,c); lane j<48 owns (z,s); wave-reduce ratios ----
__global__ __launch_bounds__(64) void reduce_kernel(
    const float* __restrict__ pd, const float* __restrict__ pn,
    float* __restrict__ out)
{
    const int bc = blockIdx.x;           // b*50 + c
    const int b = bc / 50, c = bc % 50;
    const int j = threadIdx.x;
    float ratio = 0.f;
    if (j < 48) {
        int zz = j >> 2, s = j & 3;
        size_t R = ((size_t)b * 200 + (c * 4 + s)) * 12 + zz;
        float D = 0.f, N = 0.f;
#pragma unroll
        for (int t = 0; t < 8; t++) {
            D += pd[R * 8 + t];
            N += pn[R * 8 + t];
        }
        ratio = N / D;
    }
#pragma unroll
    for (int off = 32; off; off >>= 1) ratio += __shfl_xor(ratio, off);
    if (j == 0) out[bc] = 0.25f * ratio;
}

extern "C" void kernel_launch(void* const* d_in, const int* in_sizes, int n_in,
                              void* d_out, int out_size, void* d_ws, size_t ws_size,
                              hipStream_t stream) {
    const float* Q    = (const float*)d_in[0];
    const float* H    = (const float*)d_in[1];
    const float* ql   = (const float*)d_in[2];
    const float* WQ_w = (const float*)d_in[3];
    const float* WQ_b = (const float*)d_in[4];
    const float* WK_w = (const float*)d_in[5];
    const float* WK_b = (const float*)d_in[6];
    const float* WV_w = (const float*)d_in[7];
    const float* WV_b = (const float*)d_in[8];
    float* out = (float*)d_out;

    float* ws = (float*)d_ws;                               // f32-slot offsets
    unsigned short* KSb   = (unsigned short*)ws;             // 1,572,864
    unsigned short* Hbf   = (unsigned short*)(ws + 1572864); // 1,572,864
    unsigned short* WTk   = (unsigned short*)(ws + 3145728); //   294,912
    unsigned short* WTq   = (unsigned short*)(ws + 3440640); //   294,912
    unsigned short* WTv   = (unsigned short*)(ws + 3735552); //   294,912
    unsigned short* Qbf   = (unsigned short*)(ws + 4030464); //    76,800
    unsigned short* qlbf  = (unsigned short*)(ws + 4107264); //    19,200
    unsigned short* QSbf  = (unsigned short*)(ws + 4126464); //    79,872
    unsigned short* WQLbf = (unsigned short*)(ws + 4206336); //    24,576
    float* pd             = ws + 4230912;                    //    76,800
    float* pn             = ws + 4307712;                    //    76,800
    (void)in_sizes; (void)n_in; (void)out_size; (void)ws_size;

    prep_kernel<<<2062, 256, 0, stream>>>(H, WK_w, WQ_w, WV_w, Q, ql,
                                          Hbf, WTk, WTq, WTv, Qbf, qlbf);
    gemm_all_kernel<<<420, 256, 0, stream>>>(Hbf, Qbf, qlbf, WTk, WTq, WTv,
                                             WK_b, WQ_b, WV_b, KSb, QSbf, WQLbf);
    attn7_kernel<<<384, 256, 0, stream>>>(KSb, QSbf, H, WQLbf, pd, pn);
    reduce_kernel<<<200, 64, 0, stream>>>(pd, pn, out);
}